// Round 1
// 498.044 us; speedup vs baseline: 1.0363x; 1.0363x over previous
//
#include <hip/hip_runtime.h>

// GGNN on MI355X.
// R4: old big_mm was transaction-bound (scattered 128B segments) -> frag relayout.
// R5: all hot global accesses lane-contiguous; 514.9 us. ~340 us is harness floor
//     (1GB ws poison fill + input restore) — untouchable.
// R6: fuse relayout_A into step-1 GEMM (fused_mm1): read A f32 once, stage via
//     bf16 LDS tile, MFMA directly from LDS, emit Afrag (for step 2) from the
//     already-assembled fragments. Kills the 131 MB Afrag re-read of step 1 and
//     one launch. k-split becomes uniform 5-way (25 steps); gating sums 5 planes.

typedef float  f32x4_t  __attribute__((ext_vector_type(4)));
typedef __bf16 bf16x8_t __attribute__((ext_vector_type(8)));
typedef __bf16 bf16x4_t __attribute__((ext_vector_type(4)));

#define MFMA16(a, b, c) __builtin_amdgcn_mfma_f32_16x16x32_bf16((a), (b), (c), 0, 0, 0)

static constexpr int kN     = 1000;
static constexpr int kD     = 64;
static constexpr int kAD    = 32;
static constexpr int kP     = 8000 * 64;      // floats per partial plane
static constexpr int kPl    = 5;              // k-split partial planes

__device__ __forceinline__ float4 ld4(const float* p) {
    return *reinterpret_cast<const float4*>(p);
}

__device__ __forceinline__ bf16x8_t cvt8(float4 a, float4 b) {
    bf16x8_t r;
    r[0] = (__bf16)a.x; r[1] = (__bf16)a.y; r[2] = (__bf16)a.z; r[3] = (__bf16)a.w;
    r[4] = (__bf16)b.x; r[5] = (__bf16)b.y; r[6] = (__bf16)b.z; r[7] = (__bf16)b.w;
    return r;
}

// bf16x8 of sum over kPl partial planes at stride kP
__device__ __forceinline__ bf16x8_t sum5p(const float* p) {
    float s0 = 0.f, s1 = 0.f, s2 = 0.f, s3 = 0.f;
    float s4 = 0.f, s5 = 0.f, s6 = 0.f, s7 = 0.f;
    #pragma unroll
    for (int pl = 0; pl < kPl; ++pl) {
        const float4 a0 = ld4(p + (size_t)pl * kP);
        const float4 a1 = ld4(p + (size_t)pl * kP + 4);
        s0 += a0.x; s1 += a0.y; s2 += a0.z; s3 += a0.w;
        s4 += a1.x; s5 += a1.y; s6 += a1.z; s7 += a1.w;
    }
    bf16x8_t r;
    r[0] = (__bf16)s0; r[1] = (__bf16)s1; r[2] = (__bf16)s2; r[3] = (__bf16)s3;
    r[4] = (__bf16)s4; r[5] = (__bf16)s5; r[6] = (__bf16)s6; r[7] = (__bf16)s7;
    return r;
}

__device__ __forceinline__ float sigm(float x) {
    x = fminf(fmaxf(x, -30.f), 30.f);
    return 1.0f / (1.0f + __expf(-x));
}

__device__ __forceinline__ float fast_tanh(float x) {
    x = fminf(fmaxf(x, -15.f), 15.f);
    const float e = __expf(-2.0f * x);
    return (1.0f - e) / (1.0f + e);
}

// ---------------------------------------------------------------------------
// precompute_swt: SWTfrag in MFMA B-fragment order:
//   el = ((((b*2+h)*125 + s)*4 + c)*64 + lane)*8 + j
//   holds S[f = c*16 + (lane&15)][jg = s*32 + (lane>>4)*8 + j]
// where S[f][jg=e*1000+jj] = sum_d state[b][jj][d] * W[e][f][d].
// grid 1024 = 16 jt x 4 e x 2 h x 8 b; block 256.
// ---------------------------------------------------------------------------
__global__ __launch_bounds__(256) void precompute_swt(
    const float* __restrict__ state,   // [8000][64]
    const float* __restrict__ W_in,    // [4][64][64]
    const float* __restrict__ W_out,
    __bf16* __restrict__ SWTfrag)
{
    const int bx = blockIdx.x;
    const int jt = bx & 15;
    const int e  = (bx >> 4) & 3;
    const int h  = (bx >> 6) & 1;
    const int b  = bx >> 7;
    const float* W = (h ? W_out : W_in) + e * kD * kD;

    const int tid  = threadIdx.x;
    const int w    = tid >> 6;
    const int lane = tid & 63;
    const int m    = lane & 15;
    const int q    = lane >> 4;

    __shared__ __bf16 T[64][72];  // [f][j_local], +8 pad

    const int  jj    = jt * 64 + w * 16 + m;
    const bool valid = (jj < kN);
    const float* srow = state + ((size_t)b * kN + (valid ? jj : kN - 1)) * kD + q * 8;
    float4 a0 = ld4(srow),      a1 = ld4(srow + 4);
    float4 a2 = ld4(srow + 32), a3 = ld4(srow + 36);
    if (!valid) {
        a0 = make_float4(0.f, 0.f, 0.f, 0.f); a1 = a0; a2 = a0; a3 = a0;
    }
    const bf16x8_t af0 = cvt8(a0, a1);
    const bf16x8_t af1 = cvt8(a2, a3);

    #pragma unroll
    for (int c = 0; c < 4; ++c) {
        const int f = c * 16 + m;
        const float* wrow = W + f * kD + q * 8;
        const bf16x8_t bf0 = cvt8(ld4(wrow),      ld4(wrow + 4));
        const bf16x8_t bf1 = cvt8(ld4(wrow + 32), ld4(wrow + 36));
        f32x4_t acc = {0.f, 0.f, 0.f, 0.f};
        acc = MFMA16(af0, bf0, acc);
        acc = MFMA16(af1, bf1, acc);
        const int j0 = w * 16 + q * 4;
        bf16x4_t v;
        v[0] = (__bf16)acc[0]; v[1] = (__bf16)acc[1];
        v[2] = (__bf16)acc[2]; v[3] = (__bf16)acc[3];
        *reinterpret_cast<bf16x4_t*>(&T[f][j0]) = v;
    }
    __syncthreads();

    // frag-order writeout: 8 octets x 4 c x 16 m = 512 -> 2 rounds of 256
    const int bh = b * 2 + h;
    #pragma unroll
    for (int rep = 0; rep < 2; ++rep) {
        const int m2 = tid & 15;
        const int cc = (tid >> 4) & 3;
        const int ol = (tid >> 6) + rep * 4;
        const int j0 = jt * 64 + ol * 8;
        if (j0 < kN) {
            const int jg = e * kN + j0;
            const int s  = jg >> 5;
            const int qq = (jg >> 3) & 3;
            const uint4 v = *reinterpret_cast<uint4*>(&T[cc * 16 + m2][ol * 8]);
            const size_t el = ((((size_t)bh * 125 + s) * 4 + cc) * 64 + qq * 16 + m2) * 8;
            *reinterpret_cast<uint4*>((__bf16*)SWTfrag + el) = v;
        }
    }
}

// ---------------------------------------------------------------------------
// fused_mm1: step-1 GEMM reading A (f32) directly + Afrag emission.
// grid 1280 = 16 tile x 5 kseg x 2 h x 8 b; block 256 (4 waves x 16 rows).
// Per 128-float chunk: stage 64 rows to bf16 LDS (coalesced 32B/lane reads,
// cvt at write), then per 32-float k-step: 1 LDS A-frag read (b128, bank-tiled),
// Afrag store (1KB/wave contiguous), 4 contiguous B-frag loads, 4 MFMA.
// Emits partial plane kseg of a_in_p/a_out_p.
// ---------------------------------------------------------------------------
__global__ __launch_bounds__(256, 4) void fused_mm1(
    const float* __restrict__ A,
    const __bf16* __restrict__ SWTfrag,
    __bf16* __restrict__ Afrag,
    float* __restrict__ a_in_p,        // [5][8000][64]
    float* __restrict__ a_out_p)
{
    const int bx   = blockIdx.x;
    const int tile = bx & 15;
    const int rest = bx >> 4;
    const int kseg = rest % 5;
    const int rhb  = rest / 5;
    const int h    = rhb & 1;
    const int b    = rhb >> 1;

    const int t    = threadIdx.x;
    const int wv   = t >> 6;
    const int lane = t & 63;
    const int m    = lane & 15;
    const int q    = lane >> 4;

    // +8 bf16 pad: 272B row stride keeps 16B alignment; b128 start banks
    // 4*(row+q) mod 32 tile all banks -> minimum-cycle (conflict-free) b128.
    __shared__ __bf16 L[64][136];

    const float* Abase = A + (size_t)b * kN * 8000 + h * 4000;
    const int bh = b * 2 + h;

    f32x4_t acc0 = {0.f, 0.f, 0.f, 0.f};
    f32x4_t acc1 = {0.f, 0.f, 0.f, 0.f};
    f32x4_t acc2 = {0.f, 0.f, 0.f, 0.f};
    f32x4_t acc3 = {0.f, 0.f, 0.f, 0.f};

    const __bf16* pBbase = SWTfrag + (size_t)bh * 125 * 2048 + (size_t)lane * 8;
    __bf16* pAout = Afrag +
        ((((size_t)(bh * 64 + tile * 4 + wv)) * 125) * 64 + lane) * 8;

    for (int kc = 0; kc < 800; kc += 128) {
        const int cw   = (kc < 768) ? 128 : 32;   // chunk width (floats)
        const int kabs = kseg * 800 + kc;
        if (cw == 128) {
            #pragma unroll
            for (int p = 0; p < 4; ++p) {
                const int idx = p * 256 + t;
                const int r   = idx >> 4;          // 16 threads per 128-f row
                const int c8  = idx & 15;
                int i = tile * 64 + r;
                if (i >= kN) i = kN - 1;           // dup rows; outputs masked
                const float* src = Abase + (size_t)i * 8000 + kabs + c8 * 8;
                *reinterpret_cast<bf16x8_t*>(&L[r][c8 * 8]) =
                    cvt8(ld4(src), ld4(src + 4));
            }
        } else {
            const int r  = t >> 2;                 // 4 threads per 32-f row
            const int c8 = t & 3;
            int i = tile * 64 + r;
            if (i >= kN) i = kN - 1;
            const float* src = Abase + (size_t)i * 8000 + kabs + c8 * 8;
            *reinterpret_cast<bf16x8_t*>(&L[r][c8 * 8]) =
                cvt8(ld4(src), ld4(src + 4));
        }
        __syncthreads();
        const int nst = cw >> 5;
        for (int sp = 0; sp < nst; ++sp) {
            const int s = kseg * 25 + (kc >> 5) + sp;
            const bf16x8_t af =
                *reinterpret_cast<const bf16x8_t*>(&L[wv * 16 + m][sp * 32 + q * 8]);
            // Afrag side-product for step 2 (contiguous 1KB/wave-instr)
            *reinterpret_cast<bf16x8_t*>(pAout + (size_t)s * 512) = af;

            const __bf16* pB = pBbase + (size_t)s * 2048;
            const bf16x8_t b0 = *(const bf16x8_t*)(pB);
            const bf16x8_t b1 = *(const bf16x8_t*)(pB + 512);
            const bf16x8_t b2 = *(const bf16x8_t*)(pB + 1024);
            const bf16x8_t b3 = *(const bf16x8_t*)(pB + 1536);
            acc0 = MFMA16(af, b0, acc0);
            acc1 = MFMA16(af, b1, acc1);
            acc2 = MFMA16(af, b2, acc2);
            acc3 = MFMA16(af, b3, acc3);
        }
        __syncthreads();
    }

    float* dst = (h ? a_out_p : a_in_p) + (size_t)kseg * kP + (size_t)b * kN * kD;
    const int i0 = tile * 64 + wv * 16 + q * 4;
    #pragma unroll
    for (int r = 0; r < 4; ++r) {
        const int i = i0 + r;
        if (i < kN) {
            float* drow = dst + (size_t)i * kD + m;
            drow[0]  = acc0[r];
            drow[16] = acc1[r];
            drow[32] = acc2[r];
            drow[48] = acc3[r];
        }
    }
}

// ---------------------------------------------------------------------------
// big_mm_f (step 2): a_half_p[ksp][b][i][f] = sum_{s in split} Afrag . SWTfrag
// grid 1280 = 16 tile x 2 h x 8 b x 5 ksp; block 256 (4 waves x 16 rows).
// LDS-free, barrier-free; per k-step 5 contiguous 1KB loads + 4 MFMA,
// depth-1 register prefetch. Uniform 25-step splits.
// ---------------------------------------------------------------------------
__global__ __launch_bounds__(256, 4) void big_mm_f(
    const __bf16* __restrict__ Afrag,
    const __bf16* __restrict__ SWTfrag,
    float* __restrict__ a_in_p,        // [5][8000][64]
    float* __restrict__ a_out_p)
{
    const int bx   = blockIdx.x;
    const int tile = bx & 15;
    const int h    = (bx >> 4) & 1;
    const int b    = (bx >> 5) & 7;
    const int ksp  = bx >> 8;          // 0..4
    const int t    = threadIdx.x;
    const int wv   = t >> 6;
    const int lane = t & 63;
    const int m    = lane & 15;
    const int q    = lane >> 4;

    const int s0 = ksp * 25;
    const int ns = 25;

    const int bh = b * 2 + h;
    const __bf16* pA = Afrag +
        ((((size_t)(bh * 64 + tile * 4 + wv)) * 125 + s0) * 64 + lane) * 8;
    const __bf16* pB = SWTfrag +
        (((size_t)bh * 125 + s0) * 4 * 64) * 8 + (size_t)lane * 8;

    f32x4_t acc0 = {0.f, 0.f, 0.f, 0.f};
    f32x4_t acc1 = {0.f, 0.f, 0.f, 0.f};
    f32x4_t acc2 = {0.f, 0.f, 0.f, 0.f};
    f32x4_t acc3 = {0.f, 0.f, 0.f, 0.f};

    bf16x8_t cA  = *(const bf16x8_t*)(pA);
    bf16x8_t cB0 = *(const bf16x8_t*)(pB);
    bf16x8_t cB1 = *(const bf16x8_t*)(pB + 512);
    bf16x8_t cB2 = *(const bf16x8_t*)(pB + 1024);
    bf16x8_t cB3 = *(const bf16x8_t*)(pB + 1536);

    for (int s = 0; s < ns; ++s) {
        const int adv = (s + 1 < ns) ? 1 : 0;   // last iter: reload (unused)
        pA += adv * 512;
        pB += adv * 2048;
        const bf16x8_t nA  = *(const bf16x8_t*)(pA);
        const bf16x8_t nB0 = *(const bf16x8_t*)(pB);
        const bf16x8_t nB1 = *(const bf16x8_t*)(pB + 512);
        const bf16x8_t nB2 = *(const bf16x8_t*)(pB + 1024);
        const bf16x8_t nB3 = *(const bf16x8_t*)(pB + 1536);

        acc0 = MFMA16(cA, cB0, acc0);
        acc1 = MFMA16(cA, cB1, acc1);
        acc2 = MFMA16(cA, cB2, acc2);
        acc3 = MFMA16(cA, cB3, acc3);

        cA = nA; cB0 = nB0; cB1 = nB1; cB2 = nB2; cB3 = nB3;
    }

    float* dst = (h ? a_out_p : a_in_p) + (size_t)ksp * kP + (size_t)b * kN * kD;
    const int i0 = tile * 64 + wv * 16 + q * 4;
    #pragma unroll
    for (int r = 0; r < 4; ++r) {
        const int i = i0 + r;
        if (i < kN) {
            float* drow = dst + (size_t)i * kD + m;
            drow[0]  = acc0[r];
            drow[16] = acc1[r];
            drow[32] = acc2[r];
            drow[48] = acc3[r];
        }
    }
}

// ---------------------------------------------------------------------------
// Gating, col-split: block = 256 (4 waves), 16 rows per block, wave c owns
// output cols f = c*16..c*16+15. a_in/a_out = sum of 5 K-partials.
// step 1: write next state. step 2: fused output head.
// ---------------------------------------------------------------------------
__global__ __launch_bounds__(256, 2) void gating(
    const float* __restrict__ a_in_p,   // [5][8000][64]
    const float* __restrict__ a_out_p,
    const float* __restrict__ state,
    const float* __restrict__ W_r,
    const float* __restrict__ W_z,
    const float* __restrict__ W_h,
    float* __restrict__ s_next,
    const float* __restrict__ ann,
    const float* __restrict__ Wo1,
    const float* __restrict__ Wo2,
    float* __restrict__ out,
    const int step)
{
    const int i0   = blockIdx.x * 16;
    const int tid  = threadIdx.x;
    const int c    = tid >> 6;           // wave = column slice
    const int lane = tid & 63;
    const int m    = lane & 15;
    const int q    = lane >> 4;
    const int f    = c * 16 + m;

    __shared__ __bf16 TL[16][72];
    __shared__ float  Osum[4][16];

    const size_t rowA = (size_t)(i0 + m);

    bf16x8_t xf[6];
    {
        const float* p = a_in_p + rowA * kD + q * 8;
        xf[0] = sum5p(p);
        xf[1] = sum5p(p + 32);
        p = a_out_p + rowA * kD + q * 8;
        xf[2] = sum5p(p);
        xf[3] = sum5p(p + 32);
        p = state + rowA * kD + q * 8;
        xf[4] = cvt8(ld4(p),      ld4(p + 4));
        xf[5] = cvt8(ld4(p + 32), ld4(p + 36));
    }

    f32x4_t accr = {0.f, 0.f, 0.f, 0.f};
    f32x4_t accz = {0.f, 0.f, 0.f, 0.f};
    f32x4_t acch = {0.f, 0.f, 0.f, 0.f};

    const float* wr = W_r + f * 192 + q * 8;
    const float* wz = W_z + f * 192 + q * 8;
    const float* wh = W_h + f * 192 + q * 8;
    #pragma unroll
    for (int kc = 0; kc < 6; ++kc) {
        accr = MFMA16(xf[kc], cvt8(ld4(wr + kc * 32), ld4(wr + kc * 32 + 4)), accr);
        accz = MFMA16(xf[kc], cvt8(ld4(wz + kc * 32), ld4(wz + kc * 32 + 4)), accz);
        if (kc < 4)  // h-preact uses only [a_in|a_out] here (K=128)
            acch = MFMA16(xf[kc], cvt8(ld4(wh + kc * 32), ld4(wh + kc * 32 + 4)), acch);
    }

    float sC[4];
    #pragma unroll
    for (int r = 0; r < 4; ++r)
        sC[r] = state[(size_t)(i0 + q * 4 + r) * kD + f];

    // rs = sigm(r_pre) * state -> LDS transpose (C layout -> A layout)
    #pragma unroll
    for (int r = 0; r < 4; ++r)
        TL[q * 4 + r][f] = (__bf16)(sigm(accr[r]) * sC[r]);
    __syncthreads();
    const bf16x8_t rs0 = *(const bf16x8_t*)&TL[m][q * 8];
    const bf16x8_t rs1 = *(const bf16x8_t*)&TL[m][32 + q * 8];

    const float* wh3 = W_h + f * 192 + 128 + q * 8;
    acch = MFMA16(rs0, cvt8(ld4(wh3),      ld4(wh3 + 4)),  acch);
    acch = MFMA16(rs1, cvt8(ld4(wh3 + 32), ld4(wh3 + 36)), acch);

    float ns[4];
    #pragma unroll
    for (int r = 0; r < 4; ++r) {
        const float zv = sigm(accz[r]);
        ns[r] = (1.f - zv) * sC[r] + zv * fast_tanh(acch[r]);
    }

    if (step == 1) {
        #pragma unroll
        for (int r = 0; r < 4; ++r)
            s_next[(size_t)(i0 + q * 4 + r) * kD + f] = ns[r];
    } else {
        __syncthreads();  // all waves done reading rs frags from TL
        #pragma unroll
        for (int r = 0; r < 4; ++r)
            TL[q * 4 + r][f] = (__bf16)ns[r];
        __syncthreads();
        const bf16x8_t j0 = *(const bf16x8_t*)&TL[m][q * 8];
        const bf16x8_t j1 = *(const bf16x8_t*)&TL[m][32 + q * 8];
        const float* ap = ann + rowA * kAD + q * 8;
        const bf16x8_t j2 = cvt8(ld4(ap), ld4(ap + 4));

        f32x4_t acco = {0.f, 0.f, 0.f, 0.f};
        const float* wo = Wo1 + (size_t)f * 96 + q * 8;
        acco = MFMA16(j0, cvt8(ld4(wo),      ld4(wo + 4)),  acco);
        acco = MFMA16(j1, cvt8(ld4(wo + 32), ld4(wo + 36)), acco);
        acco = MFMA16(j2, cvt8(ld4(wo + 64), ld4(wo + 68)), acco);

        const float w2 = Wo2[f];
        float vs[4];
        #pragma unroll
        for (int r = 0; r < 4; ++r)
            vs[r] = fast_tanh(acco[r]) * w2;
        #pragma unroll
        for (int off = 1; off <= 8; off <<= 1) {
            #pragma unroll
            for (int r = 0; r < 4; ++r)
                vs[r] += __shfl_xor(vs[r], off, 64);
        }
        if (m == 0) {
            #pragma unroll
            for (int r = 0; r < 4; ++r)
                Osum[c][q * 4 + r] = vs[r];
        }
        __syncthreads();
        if (tid < 16)
            out[i0 + tid] = Osum[0][tid] + Osum[1][tid] + Osum[2][tid] + Osum[3][tid];
    }
}

extern "C" void kernel_launch(void* const* d_in, const int* in_sizes, int n_in,
                              void* d_out, int out_size, void* d_ws, size_t ws_size,
                              hipStream_t stream) {
    (void)in_sizes; (void)n_in; (void)out_size; (void)ws_size;

    const float* prop_state = (const float*)d_in[0];
    const float* annotation = (const float*)d_in[1];
    const float* A          = (const float*)d_in[2];
    const float* W_in       = (const float*)d_in[3];
    const float* W_out      = (const float*)d_in[4];
    const float* W_r        = (const float*)d_in[5];
    const float* W_z        = (const float*)d_in[6];
    const float* W_h        = (const float*)d_in[7];
    const float* Wo1        = (const float*)d_in[8];
    const float* Wo2        = (const float*)d_in[9];
    float* out = (float*)d_out;

    char* ws = (char*)d_ws;
    __bf16* Afrag   = (__bf16*)(ws);                    // 131,072,000 B
    __bf16* SWTfrag = (__bf16*)(ws + 131072000);        //   8,192,000 B
    float*  a_in_p  = (float*)(ws + 139264000);         //  10,240,000 B (5 planes)
    float*  a_out_p = (float*)(ws + 149504000);         //  10,240,000 B (5 planes)
    float*  s1      = (float*)(ws + 159744000);         //   2,048,000 B

    // step 1 (fused: A read + relayout emission + GEMM)
    precompute_swt<<<1024, 256, 0, stream>>>(prop_state, W_in, W_out, SWTfrag);
    fused_mm1<<<1280, 256, 0, stream>>>(A, SWTfrag, Afrag, a_in_p, a_out_p);
    gating<<<500, 256, 0, stream>>>(a_in_p, a_out_p, prop_state, W_r, W_z, W_h,
                                    s1, nullptr, nullptr, nullptr, nullptr, 1);
    // step 2 (+ fused output head)
    precompute_swt<<<1024, 256, 0, stream>>>(s1, W_in, W_out, SWTfrag);
    big_mm_f<<<1280, 256, 0, stream>>>(Afrag, SWTfrag, a_in_p, a_out_p);
    gating<<<500, 256, 0, stream>>>(a_in_p, a_out_p, s1, W_r, W_z, W_h,
                                    nullptr, annotation, Wo1, Wo2, out, 2);
}

// Round 2
// 495.745 us; speedup vs baseline: 1.0411x; 1.0046x over previous
//
#include <hip/hip_runtime.h>

// GGNN on MI355X.
// R4: old big_mm was transaction-bound (scattered 128B segments) -> frag relayout.
// R5: all hot global accesses lane-contiguous; 514.9 us. ~340 us is harness floor
//     (1GB ws poison fill + input restore) — untouchable.
// R6: fused relayout_A into step-1 GEMM (fused_mm1); 498.0 us.
// R7: fused_mm1 made async double-buffered: loads for chunk c+1 issued right
//     after the barrier (hidden under compute of chunk c), cvt+LDS-write late,
//     ONE barrier per chunk (7 vs 14). sp-loop compile-time unrolled.

typedef float  f32x4_t  __attribute__((ext_vector_type(4)));
typedef __bf16 bf16x8_t __attribute__((ext_vector_type(8)));
typedef __bf16 bf16x4_t __attribute__((ext_vector_type(4)));

#define MFMA16(a, b, c) __builtin_amdgcn_mfma_f32_16x16x32_bf16((a), (b), (c), 0, 0, 0)

static constexpr int kN     = 1000;
static constexpr int kD     = 64;
static constexpr int kAD    = 32;
static constexpr int kP     = 8000 * 64;      // floats per partial plane
static constexpr int kPl    = 5;              // k-split partial planes

__device__ __forceinline__ float4 ld4(const float* p) {
    return *reinterpret_cast<const float4*>(p);
}

__device__ __forceinline__ bf16x8_t cvt8(float4 a, float4 b) {
    bf16x8_t r;
    r[0] = (__bf16)a.x; r[1] = (__bf16)a.y; r[2] = (__bf16)a.z; r[3] = (__bf16)a.w;
    r[4] = (__bf16)b.x; r[5] = (__bf16)b.y; r[6] = (__bf16)b.z; r[7] = (__bf16)b.w;
    return r;
}

// bf16x8 of sum over kPl partial planes at stride kP
__device__ __forceinline__ bf16x8_t sum5p(const float* p) {
    float s0 = 0.f, s1 = 0.f, s2 = 0.f, s3 = 0.f;
    float s4 = 0.f, s5 = 0.f, s6 = 0.f, s7 = 0.f;
    #pragma unroll
    for (int pl = 0; pl < kPl; ++pl) {
        const float4 a0 = ld4(p + (size_t)pl * kP);
        const float4 a1 = ld4(p + (size_t)pl * kP + 4);
        s0 += a0.x; s1 += a0.y; s2 += a0.z; s3 += a0.w;
        s4 += a1.x; s5 += a1.y; s6 += a1.z; s7 += a1.w;
    }
    bf16x8_t r;
    r[0] = (__bf16)s0; r[1] = (__bf16)s1; r[2] = (__bf16)s2; r[3] = (__bf16)s3;
    r[4] = (__bf16)s4; r[5] = (__bf16)s5; r[6] = (__bf16)s6; r[7] = (__bf16)s7;
    return r;
}

__device__ __forceinline__ float sigm(float x) {
    x = fminf(fmaxf(x, -30.f), 30.f);
    return 1.0f / (1.0f + __expf(-x));
}

__device__ __forceinline__ float fast_tanh(float x) {
    x = fminf(fmaxf(x, -15.f), 15.f);
    const float e = __expf(-2.0f * x);
    return (1.0f - e) / (1.0f + e);
}

// ---------------------------------------------------------------------------
// precompute_swt: SWTfrag in MFMA B-fragment order:
//   el = ((((b*2+h)*125 + s)*4 + c)*64 + lane)*8 + j
//   holds S[f = c*16 + (lane&15)][jg = s*32 + (lane>>4)*8 + j]
// where S[f][jg=e*1000+jj] = sum_d state[b][jj][d] * W[e][f][d].
// grid 1024 = 16 jt x 4 e x 2 h x 8 b; block 256.
// ---------------------------------------------------------------------------
__global__ __launch_bounds__(256) void precompute_swt(
    const float* __restrict__ state,   // [8000][64]
    const float* __restrict__ W_in,    // [4][64][64]
    const float* __restrict__ W_out,
    __bf16* __restrict__ SWTfrag)
{
    const int bx = blockIdx.x;
    const int jt = bx & 15;
    const int e  = (bx >> 4) & 3;
    const int h  = (bx >> 6) & 1;
    const int b  = bx >> 7;
    const float* W = (h ? W_out : W_in) + e * kD * kD;

    const int tid  = threadIdx.x;
    const int w    = tid >> 6;
    const int lane = tid & 63;
    const int m    = lane & 15;
    const int q    = lane >> 4;

    __shared__ __bf16 T[64][72];  // [f][j_local], +8 pad

    const int  jj    = jt * 64 + w * 16 + m;
    const bool valid = (jj < kN);
    const float* srow = state + ((size_t)b * kN + (valid ? jj : kN - 1)) * kD + q * 8;
    float4 a0 = ld4(srow),      a1 = ld4(srow + 4);
    float4 a2 = ld4(srow + 32), a3 = ld4(srow + 36);
    if (!valid) {
        a0 = make_float4(0.f, 0.f, 0.f, 0.f); a1 = a0; a2 = a0; a3 = a0;
    }
    const bf16x8_t af0 = cvt8(a0, a1);
    const bf16x8_t af1 = cvt8(a2, a3);

    #pragma unroll
    for (int c = 0; c < 4; ++c) {
        const int f = c * 16 + m;
        const float* wrow = W + f * kD + q * 8;
        const bf16x8_t bf0 = cvt8(ld4(wrow),      ld4(wrow + 4));
        const bf16x8_t bf1 = cvt8(ld4(wrow + 32), ld4(wrow + 36));
        f32x4_t acc = {0.f, 0.f, 0.f, 0.f};
        acc = MFMA16(af0, bf0, acc);
        acc = MFMA16(af1, bf1, acc);
        const int j0 = w * 16 + q * 4;
        bf16x4_t v;
        v[0] = (__bf16)acc[0]; v[1] = (__bf16)acc[1];
        v[2] = (__bf16)acc[2]; v[3] = (__bf16)acc[3];
        *reinterpret_cast<bf16x4_t*>(&T[f][j0]) = v;
    }
    __syncthreads();

    // frag-order writeout: 8 octets x 4 c x 16 m = 512 -> 2 rounds of 256
    const int bh = b * 2 + h;
    #pragma unroll
    for (int rep = 0; rep < 2; ++rep) {
        const int m2 = tid & 15;
        const int cc = (tid >> 4) & 3;
        const int ol = (tid >> 6) + rep * 4;
        const int j0 = jt * 64 + ol * 8;
        if (j0 < kN) {
            const int jg = e * kN + j0;
            const int s  = jg >> 5;
            const int qq = (jg >> 3) & 3;
            const uint4 v = *reinterpret_cast<uint4*>(&T[cc * 16 + m2][ol * 8]);
            const size_t el = ((((size_t)bh * 125 + s) * 4 + cc) * 64 + qq * 16 + m2) * 8;
            *reinterpret_cast<uint4*>((__bf16*)SWTfrag + el) = v;
        }
    }
}

// ---------------------------------------------------------------------------
// fused_mm1: step-1 GEMM reading A (f32) directly + Afrag emission.
// grid 1280 = 16 tile x 5 kseg x 2 h x 8 b; block 256 (4 waves x 16 rows).
// Async double-buffered staging: chunk c+1's global loads issue right after
// the barrier and are hidden under chunk c's compute (16 MFMA + Afrag store +
// B loads); cvt + LDS write happen post-compute; 1 barrier per chunk.
// Chunks: 6 x 128 floats + 1 x 32 floats = 800 (25 k-steps).
// ---------------------------------------------------------------------------
__global__ __launch_bounds__(256, 4) void fused_mm1(
    const float* __restrict__ A,
    const __bf16* __restrict__ SWTfrag,
    __bf16* __restrict__ Afrag,
    float* __restrict__ a_in_p,        // [5][8000][64]
    float* __restrict__ a_out_p)
{
    const int bx   = blockIdx.x;
    const int tile = bx & 15;
    const int rest = bx >> 4;
    const int kseg = rest % 5;
    const int rhb  = rest / 5;
    const int h    = rhb & 1;
    const int b    = rhb >> 1;

    const int t    = threadIdx.x;
    const int wv   = t >> 6;
    const int lane = t & 63;
    const int m    = lane & 15;
    const int q    = lane >> 4;

    // +8 bf16 pad: 272B row stride keeps 16B alignment and staggers banks.
    __shared__ __bf16 L[2][64][136];

    const float* Abase = A + (size_t)b * kN * 8000 + h * 4000;
    const int bh = b * 2 + h;

    f32x4_t acc0 = {0.f, 0.f, 0.f, 0.f};
    f32x4_t acc1 = {0.f, 0.f, 0.f, 0.f};
    f32x4_t acc2 = {0.f, 0.f, 0.f, 0.f};
    f32x4_t acc3 = {0.f, 0.f, 0.f, 0.f};

    const __bf16* pBbase = SWTfrag + (size_t)bh * 125 * 2048 + (size_t)lane * 8;
    __bf16* pAout = Afrag +
        ((((size_t)(bh * 64 + tile * 4 + wv)) * 125) * 64 + lane) * 8;

    float4 ra[4][2];   // staged A registers (32B/thread/round)

    // chunk c: kabs = kseg*800 + c*128; main chunks c<6 are 128 floats wide
    // (4 rounds: r = idx>>4, c8 = idx&15), tail c==6 is 32 floats
    // (1 round: r = t>>2, c8 = t&3).
    auto load_chunk = [&](int c, bool tail) {
        const int kabs = kseg * 800 + c * 128;
        #pragma unroll
        for (int p = 0; p < 4; ++p) {
            if (p == 0 || !tail) {
                const int idx = p * 256 + t;
                const int r   = tail ? (t >> 2) : (idx >> 4);
                const int c8  = tail ? (t & 3)  : (idx & 15);
                int i = tile * 64 + r;
                if (i >= kN) i = kN - 1;           // dup rows; outputs masked
                const float* src = Abase + (size_t)i * 8000 + kabs + c8 * 8;
                ra[p][0] = ld4(src);
                ra[p][1] = ld4(src + 4);
            }
        }
    };
    auto write_chunk = [&](int buf, bool tail) {
        #pragma unroll
        for (int p = 0; p < 4; ++p) {
            if (p == 0 || !tail) {
                const int idx = p * 256 + t;
                const int r   = tail ? (t >> 2) : (idx >> 4);
                const int c8  = tail ? (t & 3)  : (idx & 15);
                *reinterpret_cast<bf16x8_t*>(&L[buf][r][c8 * 8]) =
                    cvt8(ra[p][0], ra[p][1]);
            }
        }
    };
    auto compute_chunk = [&](int c, int nst, int buf) {
        #pragma unroll
        for (int sp = 0; sp < 4; ++sp) {
            if (sp < nst) {
                const int s = kseg * 25 + c * 4 + sp;
                const bf16x8_t af =
                    *reinterpret_cast<const bf16x8_t*>(&L[buf][wv * 16 + m][sp * 32 + q * 8]);
                // Afrag side-product for step 2 (contiguous 1KB/wave-instr)
                *reinterpret_cast<bf16x8_t*>(pAout + (size_t)s * 512) = af;

                const __bf16* pB = pBbase + (size_t)s * 2048;
                const bf16x8_t b0 = *(const bf16x8_t*)(pB);
                const bf16x8_t b1 = *(const bf16x8_t*)(pB + 512);
                const bf16x8_t b2 = *(const bf16x8_t*)(pB + 1024);
                const bf16x8_t b3 = *(const bf16x8_t*)(pB + 1536);
                acc0 = MFMA16(af, b0, acc0);
                acc1 = MFMA16(af, b1, acc1);
                acc2 = MFMA16(af, b2, acc2);
                acc3 = MFMA16(af, b3, acc3);
            }
        }
    };

    // prologue
    load_chunk(0, false);
    write_chunk(0, false);
    __syncthreads();
    load_chunk(1, false);

    #pragma unroll 1
    for (int c = 0; c < 6; ++c) {
        compute_chunk(c, 4, c & 1);            // hides loads for chunk c+1
        write_chunk((c + 1) & 1, c + 1 == 6);  // cvt + LDS write (loads done)
        __syncthreads();
        if (c < 5)
            load_chunk(c + 2, c + 2 == 6);     // issue next; hidden by compute
    }
    compute_chunk(6, 1, 0);                    // tail chunk (6&1 == 0)

    float* dst = (h ? a_out_p : a_in_p) + (size_t)kseg * kP + (size_t)b * kN * kD;
    const int i0 = tile * 64 + wv * 16 + q * 4;
    #pragma unroll
    for (int r = 0; r < 4; ++r) {
        const int i = i0 + r;
        if (i < kN) {
            float* drow = dst + (size_t)i * kD + m;
            drow[0]  = acc0[r];
            drow[16] = acc1[r];
            drow[32] = acc2[r];
            drow[48] = acc3[r];
        }
    }
}

// ---------------------------------------------------------------------------
// big_mm_f (step 2): a_half_p[ksp][b][i][f] = sum_{s in split} Afrag . SWTfrag
// grid 1280 = 16 tile x 2 h x 8 b x 5 ksp; block 256 (4 waves x 16 rows).
// LDS-free, barrier-free; per k-step 5 contiguous 1KB loads + 4 MFMA,
// depth-1 register prefetch. Uniform 25-step splits.
// ---------------------------------------------------------------------------
__global__ __launch_bounds__(256, 4) void big_mm_f(
    const __bf16* __restrict__ Afrag,
    const __bf16* __restrict__ SWTfrag,
    float* __restrict__ a_in_p,        // [5][8000][64]
    float* __restrict__ a_out_p)
{
    const int bx   = blockIdx.x;
    const int tile = bx & 15;
    const int h    = (bx >> 4) & 1;
    const int b    = (bx >> 5) & 7;
    const int ksp  = bx >> 8;          // 0..4
    const int t    = threadIdx.x;
    const int wv   = t >> 6;
    const int lane = t & 63;
    const int m    = lane & 15;
    const int q    = lane >> 4;

    const int s0 = ksp * 25;
    const int ns = 25;

    const int bh = b * 2 + h;
    const __bf16* pA = Afrag +
        ((((size_t)(bh * 64 + tile * 4 + wv)) * 125 + s0) * 64 + lane) * 8;
    const __bf16* pB = SWTfrag +
        (((size_t)bh * 125 + s0) * 4 * 64) * 8 + (size_t)lane * 8;

    f32x4_t acc0 = {0.f, 0.f, 0.f, 0.f};
    f32x4_t acc1 = {0.f, 0.f, 0.f, 0.f};
    f32x4_t acc2 = {0.f, 0.f, 0.f, 0.f};
    f32x4_t acc3 = {0.f, 0.f, 0.f, 0.f};

    bf16x8_t cA  = *(const bf16x8_t*)(pA);
    bf16x8_t cB0 = *(const bf16x8_t*)(pB);
    bf16x8_t cB1 = *(const bf16x8_t*)(pB + 512);
    bf16x8_t cB2 = *(const bf16x8_t*)(pB + 1024);
    bf16x8_t cB3 = *(const bf16x8_t*)(pB + 1536);

    for (int s = 0; s < ns; ++s) {
        const int adv = (s + 1 < ns) ? 1 : 0;   // last iter: reload (unused)
        pA += adv * 512;
        pB += adv * 2048;
        const bf16x8_t nA  = *(const bf16x8_t*)(pA);
        const bf16x8_t nB0 = *(const bf16x8_t*)(pB);
        const bf16x8_t nB1 = *(const bf16x8_t*)(pB + 512);
        const bf16x8_t nB2 = *(const bf16x8_t*)(pB + 1024);
        const bf16x8_t nB3 = *(const bf16x8_t*)(pB + 1536);

        acc0 = MFMA16(cA, cB0, acc0);
        acc1 = MFMA16(cA, cB1, acc1);
        acc2 = MFMA16(cA, cB2, acc2);
        acc3 = MFMA16(cA, cB3, acc3);

        cA = nA; cB0 = nB0; cB1 = nB1; cB2 = nB2; cB3 = nB3;
    }

    float* dst = (h ? a_out_p : a_in_p) + (size_t)ksp * kP + (size_t)b * kN * kD;
    const int i0 = tile * 64 + wv * 16 + q * 4;
    #pragma unroll
    for (int r = 0; r < 4; ++r) {
        const int i = i0 + r;
        if (i < kN) {
            float* drow = dst + (size_t)i * kD + m;
            drow[0]  = acc0[r];
            drow[16] = acc1[r];
            drow[32] = acc2[r];
            drow[48] = acc3[r];
        }
    }
}

// ---------------------------------------------------------------------------
// Gating, col-split: block = 256 (4 waves), 16 rows per block, wave c owns
// output cols f = c*16..c*16+15. a_in/a_out = sum of 5 K-partials.
// step 1: write next state. step 2: fused output head.
// ---------------------------------------------------------------------------
__global__ __launch_bounds__(256, 2) void gating(
    const float* __restrict__ a_in_p,   // [5][8000][64]
    const float* __restrict__ a_out_p,
    const float* __restrict__ state,
    const float* __restrict__ W_r,
    const float* __restrict__ W_z,
    const float* __restrict__ W_h,
    float* __restrict__ s_next,
    const float* __restrict__ ann,
    const float* __restrict__ Wo1,
    const float* __restrict__ Wo2,
    float* __restrict__ out,
    const int step)
{
    const int i0   = blockIdx.x * 16;
    const int tid  = threadIdx.x;
    const int c    = tid >> 6;           // wave = column slice
    const int lane = tid & 63;
    const int m    = lane & 15;
    const int q    = lane >> 4;
    const int f    = c * 16 + m;

    __shared__ __bf16 TL[16][72];
    __shared__ float  Osum[4][16];

    const size_t rowA = (size_t)(i0 + m);

    bf16x8_t xf[6];
    {
        const float* p = a_in_p + rowA * kD + q * 8;
        xf[0] = sum5p(p);
        xf[1] = sum5p(p + 32);
        p = a_out_p + rowA * kD + q * 8;
        xf[2] = sum5p(p);
        xf[3] = sum5p(p + 32);
        p = state + rowA * kD + q * 8;
        xf[4] = cvt8(ld4(p),      ld4(p + 4));
        xf[5] = cvt8(ld4(p + 32), ld4(p + 36));
    }

    f32x4_t accr = {0.f, 0.f, 0.f, 0.f};
    f32x4_t accz = {0.f, 0.f, 0.f, 0.f};
    f32x4_t acch = {0.f, 0.f, 0.f, 0.f};

    const float* wr = W_r + f * 192 + q * 8;
    const float* wz = W_z + f * 192 + q * 8;
    const float* wh = W_h + f * 192 + q * 8;
    #pragma unroll
    for (int kc = 0; kc < 6; ++kc) {
        accr = MFMA16(xf[kc], cvt8(ld4(wr + kc * 32), ld4(wr + kc * 32 + 4)), accr);
        accz = MFMA16(xf[kc], cvt8(ld4(wz + kc * 32), ld4(wz + kc * 32 + 4)), accz);
        if (kc < 4)  // h-preact uses only [a_in|a_out] here (K=128)
            acch = MFMA16(xf[kc], cvt8(ld4(wh + kc * 32), ld4(wh + kc * 32 + 4)), acch);
    }

    float sC[4];
    #pragma unroll
    for (int r = 0; r < 4; ++r)
        sC[r] = state[(size_t)(i0 + q * 4 + r) * kD + f];

    // rs = sigm(r_pre) * state -> LDS transpose (C layout -> A layout)
    #pragma unroll
    for (int r = 0; r < 4; ++r)
        TL[q * 4 + r][f] = (__bf16)(sigm(accr[r]) * sC[r]);
    __syncthreads();
    const bf16x8_t rs0 = *(const bf16x8_t*)&TL[m][q * 8];
    const bf16x8_t rs1 = *(const bf16x8_t*)&TL[m][32 + q * 8];

    const float* wh3 = W_h + f * 192 + 128 + q * 8;
    acch = MFMA16(rs0, cvt8(ld4(wh3),      ld4(wh3 + 4)),  acch);
    acch = MFMA16(rs1, cvt8(ld4(wh3 + 32), ld4(wh3 + 36)), acch);

    float ns[4];
    #pragma unroll
    for (int r = 0; r < 4; ++r) {
        const float zv = sigm(accz[r]);
        ns[r] = (1.f - zv) * sC[r] + zv * fast_tanh(acch[r]);
    }

    if (step == 1) {
        #pragma unroll
        for (int r = 0; r < 4; ++r)
            s_next[(size_t)(i0 + q * 4 + r) * kD + f] = ns[r];
    } else {
        __syncthreads();  // all waves done reading rs frags from TL
        #pragma unroll
        for (int r = 0; r < 4; ++r)
            TL[q * 4 + r][f] = (__bf16)ns[r];
        __syncthreads();
        const bf16x8_t j0 = *(const bf16x8_t*)&TL[m][q * 8];
        const bf16x8_t j1 = *(const bf16x8_t*)&TL[m][32 + q * 8];
        const float* ap = ann + rowA * kAD + q * 8;
        const bf16x8_t j2 = cvt8(ld4(ap), ld4(ap + 4));

        f32x4_t acco = {0.f, 0.f, 0.f, 0.f};
        const float* wo = Wo1 + (size_t)f * 96 + q * 8;
        acco = MFMA16(j0, cvt8(ld4(wo),      ld4(wo + 4)),  acco);
        acco = MFMA16(j1, cvt8(ld4(wo + 32), ld4(wo + 36)), acco);
        acco = MFMA16(j2, cvt8(ld4(wo + 64), ld4(wo + 68)), acco);

        const float w2 = Wo2[f];
        float vs[4];
        #pragma unroll
        for (int r = 0; r < 4; ++r)
            vs[r] = fast_tanh(acco[r]) * w2;
        #pragma unroll
        for (int off = 1; off <= 8; off <<= 1) {
            #pragma unroll
            for (int r = 0; r < 4; ++r)
                vs[r] += __shfl_xor(vs[r], off, 64);
        }
        if (m == 0) {
            #pragma unroll
            for (int r = 0; r < 4; ++r)
                Osum[c][q * 4 + r] = vs[r];
        }
        __syncthreads();
        if (tid < 16)
            out[i0 + tid] = Osum[0][tid] + Osum[1][tid] + Osum[2][tid] + Osum[3][tid];
    }
}

extern "C" void kernel_launch(void* const* d_in, const int* in_sizes, int n_in,
                              void* d_out, int out_size, void* d_ws, size_t ws_size,
                              hipStream_t stream) {
    (void)in_sizes; (void)n_in; (void)out_size; (void)ws_size;

    const float* prop_state = (const float*)d_in[0];
    const float* annotation = (const float*)d_in[1];
    const float* A          = (const float*)d_in[2];
    const float* W_in       = (const float*)d_in[3];
    const float* W_out      = (const float*)d_in[4];
    const float* W_r        = (const float*)d_in[5];
    const float* W_z        = (const float*)d_in[6];
    const float* W_h        = (const float*)d_in[7];
    const float* Wo1        = (const float*)d_in[8];
    const float* Wo2        = (const float*)d_in[9];
    float* out = (float*)d_out;

    char* ws = (char*)d_ws;
    __bf16* Afrag   = (__bf16*)(ws);                    // 131,072,000 B
    __bf16* SWTfrag = (__bf16*)(ws + 131072000);        //   8,192,000 B
    float*  a_in_p  = (float*)(ws + 139264000);         //  10,240,000 B (5 planes)
    float*  a_out_p = (float*)(ws + 149504000);         //  10,240,000 B (5 planes)
    float*  s1      = (float*)(ws + 159744000);         //   2,048,000 B

    // step 1 (fused: A read + relayout emission + GEMM)
    precompute_swt<<<1024, 256, 0, stream>>>(prop_state, W_in, W_out, SWTfrag);
    fused_mm1<<<1280, 256, 0, stream>>>(A, SWTfrag, Afrag, a_in_p, a_out_p);
    gating<<<500, 256, 0, stream>>>(a_in_p, a_out_p, prop_state, W_r, W_z, W_h,
                                    s1, nullptr, nullptr, nullptr, nullptr, 1);
    // step 2 (+ fused output head)
    precompute_swt<<<1024, 256, 0, stream>>>(s1, W_in, W_out, SWTfrag);
    big_mm_f<<<1280, 256, 0, stream>>>(Afrag, SWTfrag, a_in_p, a_out_p);
    gating<<<500, 256, 0, stream>>>(a_in_p, a_out_p, s1, W_r, W_z, W_h,
                                    nullptr, annotation, Wo1, Wo2, out, 2);
}

// Round 3
// 481.695 us; speedup vs baseline: 1.0715x; 1.0292x over previous
//
#include <hip/hip_runtime.h>

// GGNN on MI355X.
// R4: old big_mm was transaction-bound (scattered 128B segments) -> frag relayout.
// R5: all hot global accesses lane-contiguous; 514.9 us. ~340 us is harness floor
//     (1GB ws poison fill + input restore) — untouchable.
// R6: fused relayout_A into step-1 GEMM (fused_mm1); 498.0 us.
// R7: async double-buffer in fused_mm1; only -2.3 us -> it is mixed-BW-bound,
//     not latency-bound. 495.7 us.
// R8: cut bytes + dispatches: (1) partial planes stored bf16 (gating quantized
//     them to bf16 anyway) via wave-private LDS transpose for coalesced stores;
//     (2) precompute_swt(step2) fused into gating step 1 (bit-identical SWT
//     emission from the s1 rows already in registers). 5 dispatches.

typedef float  f32x4_t  __attribute__((ext_vector_type(4)));
typedef __bf16 bf16x8_t __attribute__((ext_vector_type(8)));
typedef __bf16 bf16x4_t __attribute__((ext_vector_type(4)));

#define MFMA16(a, b, c) __builtin_amdgcn_mfma_f32_16x16x32_bf16((a), (b), (c), 0, 0, 0)

static constexpr int kN   = 1000;
static constexpr int kD   = 64;
static constexpr int kAD  = 32;
static constexpr int kPb  = 8000 * 64;   // bf16 elems per partial plane
static constexpr int kPl  = 5;           // k-split partial planes

__device__ __forceinline__ float4 ld4(const float* p) {
    return *reinterpret_cast<const float4*>(p);
}

__device__ __forceinline__ bf16x8_t cvt8(float4 a, float4 b) {
    bf16x8_t r;
    r[0] = (__bf16)a.x; r[1] = (__bf16)a.y; r[2] = (__bf16)a.z; r[3] = (__bf16)a.w;
    r[4] = (__bf16)b.x; r[5] = (__bf16)b.y; r[6] = (__bf16)b.z; r[7] = (__bf16)b.w;
    return r;
}

// bf16x8 of f32-sum over kPl bf16 partial planes at stride kPb
__device__ __forceinline__ bf16x8_t sum5pb(const __bf16* p) {
    float s0 = 0.f, s1 = 0.f, s2 = 0.f, s3 = 0.f;
    float s4 = 0.f, s5 = 0.f, s6 = 0.f, s7 = 0.f;
    #pragma unroll
    for (int pl = 0; pl < kPl; ++pl) {
        const bf16x8_t v = *reinterpret_cast<const bf16x8_t*>(p + (size_t)pl * kPb);
        s0 += (float)v[0]; s1 += (float)v[1]; s2 += (float)v[2]; s3 += (float)v[3];
        s4 += (float)v[4]; s5 += (float)v[5]; s6 += (float)v[6]; s7 += (float)v[7];
    }
    bf16x8_t r;
    r[0] = (__bf16)s0; r[1] = (__bf16)s1; r[2] = (__bf16)s2; r[3] = (__bf16)s3;
    r[4] = (__bf16)s4; r[5] = (__bf16)s5; r[6] = (__bf16)s6; r[7] = (__bf16)s7;
    return r;
}

__device__ __forceinline__ float sigm(float x) {
    x = fminf(fmaxf(x, -30.f), 30.f);
    return 1.0f / (1.0f + __expf(-x));
}

__device__ __forceinline__ float fast_tanh(float x) {
    x = fminf(fmaxf(x, -15.f), 15.f);
    const float e = __expf(-2.0f * x);
    return (1.0f - e) / (1.0f + e);
}

// ---------------------------------------------------------------------------
// precompute_swt (step 1 only): SWTfrag in MFMA B-fragment order:
//   el = ((((b*2+h)*125 + s)*4 + c)*64 + lane)*8 + j
//   holds S[f = c*16 + (lane&15)][jg = s*32 + (lane>>4)*8 + j]
// grid 1024 = 16 jt x 4 e x 2 h x 8 b; block 256.
// ---------------------------------------------------------------------------
__global__ __launch_bounds__(256) void precompute_swt(
    const float* __restrict__ state,   // [8000][64]
    const float* __restrict__ W_in,    // [4][64][64]
    const float* __restrict__ W_out,
    __bf16* __restrict__ SWTfrag)
{
    const int bx = blockIdx.x;
    const int jt = bx & 15;
    const int e  = (bx >> 4) & 3;
    const int h  = (bx >> 6) & 1;
    const int b  = bx >> 7;
    const float* W = (h ? W_out : W_in) + e * kD * kD;

    const int tid  = threadIdx.x;
    const int w    = tid >> 6;
    const int lane = tid & 63;
    const int m    = lane & 15;
    const int q    = lane >> 4;

    __shared__ __bf16 T[64][72];  // [f][j_local], +8 pad

    const int  jj    = jt * 64 + w * 16 + m;
    const bool valid = (jj < kN);
    const float* srow = state + ((size_t)b * kN + (valid ? jj : kN - 1)) * kD + q * 8;
    float4 a0 = ld4(srow),      a1 = ld4(srow + 4);
    float4 a2 = ld4(srow + 32), a3 = ld4(srow + 36);
    if (!valid) {
        a0 = make_float4(0.f, 0.f, 0.f, 0.f); a1 = a0; a2 = a0; a3 = a0;
    }
    const bf16x8_t af0 = cvt8(a0, a1);
    const bf16x8_t af1 = cvt8(a2, a3);

    #pragma unroll
    for (int c = 0; c < 4; ++c) {
        const int f = c * 16 + m;
        const float* wrow = W + f * kD + q * 8;
        const bf16x8_t bf0 = cvt8(ld4(wrow),      ld4(wrow + 4));
        const bf16x8_t bf1 = cvt8(ld4(wrow + 32), ld4(wrow + 36));
        f32x4_t acc = {0.f, 0.f, 0.f, 0.f};
        acc = MFMA16(af0, bf0, acc);
        acc = MFMA16(af1, bf1, acc);
        const int j0 = w * 16 + q * 4;
        bf16x4_t v;
        v[0] = (__bf16)acc[0]; v[1] = (__bf16)acc[1];
        v[2] = (__bf16)acc[2]; v[3] = (__bf16)acc[3];
        *reinterpret_cast<bf16x4_t*>(&T[f][j0]) = v;
    }
    __syncthreads();

    const int bh = b * 2 + h;
    #pragma unroll
    for (int rep = 0; rep < 2; ++rep) {
        const int m2 = tid & 15;
        const int cc = (tid >> 4) & 3;
        const int ol = (tid >> 6) + rep * 4;
        const int j0 = jt * 64 + ol * 8;
        if (j0 < kN) {
            const int jg = e * kN + j0;
            const int s  = jg >> 5;
            const int qq = (jg >> 3) & 3;
            const uint4 v = *reinterpret_cast<uint4*>(&T[cc * 16 + m2][ol * 8]);
            const size_t el = ((((size_t)bh * 125 + s) * 4 + cc) * 64 + qq * 16 + m2) * 8;
            *reinterpret_cast<uint4*>((__bf16*)SWTfrag + el) = v;
        }
    }
}

// ---------------------------------------------------------------------------
// fused_mm1: step-1 GEMM reading A (f32) directly + Afrag emission.
// grid 1280 = 16 tile x 5 kseg x 2 h x 8 b; block 256 (4 waves x 16 rows).
// Async double-buffered staging; 1 barrier per chunk. Partial-plane output in
// bf16 via per-wave LDS transpose (reuses L[0] cols 64..127, no extra barrier).
// ---------------------------------------------------------------------------
__global__ __launch_bounds__(256, 4) void fused_mm1(
    const float* __restrict__ A,
    const __bf16* __restrict__ SWTfrag,
    __bf16* __restrict__ Afrag,
    __bf16* __restrict__ a_in_p,       // [5][8000][64] bf16
    __bf16* __restrict__ a_out_p)
{
    const int bx   = blockIdx.x;
    const int tile = bx & 15;
    const int rest = bx >> 4;
    const int kseg = rest % 5;
    const int rhb  = rest / 5;
    const int h    = rhb & 1;
    const int b    = rhb >> 1;

    const int t    = threadIdx.x;
    const int wv   = t >> 6;
    const int lane = t & 63;
    const int m    = lane & 15;
    const int q    = lane >> 4;

    __shared__ __bf16 L[2][64][136];   // 272B row stride: 16B-aligned, staggered

    const float* Abase = A + (size_t)b * kN * 8000 + h * 4000;
    const int bh = b * 2 + h;

    f32x4_t acc0 = {0.f, 0.f, 0.f, 0.f};
    f32x4_t acc1 = {0.f, 0.f, 0.f, 0.f};
    f32x4_t acc2 = {0.f, 0.f, 0.f, 0.f};
    f32x4_t acc3 = {0.f, 0.f, 0.f, 0.f};

    const __bf16* pBbase = SWTfrag + (size_t)bh * 125 * 2048 + (size_t)lane * 8;
    __bf16* pAout = Afrag +
        ((((size_t)(bh * 64 + tile * 4 + wv)) * 125) * 64 + lane) * 8;

    float4 ra[4][2];   // staged A registers (32B/thread/round)

    auto load_chunk = [&](int c, bool tail) {
        const int kabs = kseg * 800 + c * 128;
        #pragma unroll
        for (int p = 0; p < 4; ++p) {
            if (p == 0 || !tail) {
                const int idx = p * 256 + t;
                const int r   = tail ? (t >> 2) : (idx >> 4);
                const int c8  = tail ? (t & 3)  : (idx & 15);
                int i = tile * 64 + r;
                if (i >= kN) i = kN - 1;           // dup rows; outputs masked
                const float* src = Abase + (size_t)i * 8000 + kabs + c8 * 8;
                ra[p][0] = ld4(src);
                ra[p][1] = ld4(src + 4);
            }
        }
    };
    auto write_chunk = [&](int buf, bool tail) {
        #pragma unroll
        for (int p = 0; p < 4; ++p) {
            if (p == 0 || !tail) {
                const int idx = p * 256 + t;
                const int r   = tail ? (t >> 2) : (idx >> 4);
                const int c8  = tail ? (t & 3)  : (idx & 15);
                *reinterpret_cast<bf16x8_t*>(&L[buf][r][c8 * 8]) =
                    cvt8(ra[p][0], ra[p][1]);
            }
        }
    };
    auto compute_chunk = [&](int c, int nst, int buf) {
        #pragma unroll
        for (int sp = 0; sp < 4; ++sp) {
            if (sp < nst) {
                const int s = kseg * 25 + c * 4 + sp;
                const bf16x8_t af =
                    *reinterpret_cast<const bf16x8_t*>(&L[buf][wv * 16 + m][sp * 32 + q * 8]);
                *reinterpret_cast<bf16x8_t*>(pAout + (size_t)s * 512) = af;

                const __bf16* pB = pBbase + (size_t)s * 2048;
                const bf16x8_t b0 = *(const bf16x8_t*)(pB);
                const bf16x8_t b1 = *(const bf16x8_t*)(pB + 512);
                const bf16x8_t b2 = *(const bf16x8_t*)(pB + 1024);
                const bf16x8_t b3 = *(const bf16x8_t*)(pB + 1536);
                acc0 = MFMA16(af, b0, acc0);
                acc1 = MFMA16(af, b1, acc1);
                acc2 = MFMA16(af, b2, acc2);
                acc3 = MFMA16(af, b3, acc3);
            }
        }
    };

    load_chunk(0, false);
    write_chunk(0, false);
    __syncthreads();
    load_chunk(1, false);

    #pragma unroll 1
    for (int c = 0; c < 6; ++c) {
        compute_chunk(c, 4, c & 1);
        write_chunk((c + 1) & 1, c + 1 == 6);
        __syncthreads();
        if (c < 5)
            load_chunk(c + 2, c + 2 == 6);
    }
    compute_chunk(6, 1, 0);   // tail reads L[0] cols 0..31 only

    // wave-private bf16 transpose in L[0] cols 64..127 (disjoint from tail read)
    __bf16* Tw = &L[0][wv * 16][64];   // 16 rows x 64 cols, row stride 136
    #pragma unroll
    for (int r = 0; r < 4; ++r) {
        const int row = q * 4 + r;
        Tw[row * 136 + m]      = (__bf16)acc0[r];
        Tw[row * 136 + 16 + m] = (__bf16)acc1[r];
        Tw[row * 136 + 32 + m] = (__bf16)acc2[r];
        Tw[row * 136 + 48 + m] = (__bf16)acc3[r];
    }
    __bf16* dstb = (h ? a_out_p : a_in_p) + (size_t)kseg * kPb + (size_t)b * kN * kD;
    const int ibase = tile * 64 + wv * 16;
    #pragma unroll
    for (int p2 = 0; p2 < 2; ++p2) {
        const int jr = p2 * 8 + (lane >> 3);
        const int c8 = lane & 7;
        const int i  = ibase + jr;
        if (i < kN) {
            const bf16x8_t v = *reinterpret_cast<const bf16x8_t*>(&Tw[jr * 136 + c8 * 8]);
            *reinterpret_cast<bf16x8_t*>(dstb + (size_t)i * kD + c8 * 8) = v;
        }
    }
}

// ---------------------------------------------------------------------------
// big_mm_f (step 2): grid 1280 = 16 tile x 2 h x 8 b x 5 ksp; block 256.
// Barrier-free stream; depth-1 register prefetch; bf16 partial output via
// wave-private LDS transpose.
// ---------------------------------------------------------------------------
__global__ __launch_bounds__(256, 4) void big_mm_f(
    const __bf16* __restrict__ Afrag,
    const __bf16* __restrict__ SWTfrag,
    __bf16* __restrict__ a_in_p,       // [5][8000][64] bf16
    __bf16* __restrict__ a_out_p)
{
    const int bx   = blockIdx.x;
    const int tile = bx & 15;
    const int h    = (bx >> 4) & 1;
    const int b    = (bx >> 5) & 7;
    const int ksp  = bx >> 8;          // 0..4
    const int t    = threadIdx.x;
    const int wv   = t >> 6;
    const int lane = t & 63;
    const int m    = lane & 15;
    const int q    = lane >> 4;

    __shared__ __bf16 T[4][16][72];    // per-wave C transpose (144B rows, 16B-aligned)

    const int s0 = ksp * 25;
    const int ns = 25;

    const int bh = b * 2 + h;
    const __bf16* pA = Afrag +
        ((((size_t)(bh * 64 + tile * 4 + wv)) * 125 + s0) * 64 + lane) * 8;
    const __bf16* pB = SWTfrag +
        (((size_t)bh * 125 + s0) * 4 * 64) * 8 + (size_t)lane * 8;

    f32x4_t acc0 = {0.f, 0.f, 0.f, 0.f};
    f32x4_t acc1 = {0.f, 0.f, 0.f, 0.f};
    f32x4_t acc2 = {0.f, 0.f, 0.f, 0.f};
    f32x4_t acc3 = {0.f, 0.f, 0.f, 0.f};

    bf16x8_t cA  = *(const bf16x8_t*)(pA);
    bf16x8_t cB0 = *(const bf16x8_t*)(pB);
    bf16x8_t cB1 = *(const bf16x8_t*)(pB + 512);
    bf16x8_t cB2 = *(const bf16x8_t*)(pB + 1024);
    bf16x8_t cB3 = *(const bf16x8_t*)(pB + 1536);

    for (int s = 0; s < ns; ++s) {
        const int adv = (s + 1 < ns) ? 1 : 0;
        pA += adv * 512;
        pB += adv * 2048;
        const bf16x8_t nA  = *(const bf16x8_t*)(pA);
        const bf16x8_t nB0 = *(const bf16x8_t*)(pB);
        const bf16x8_t nB1 = *(const bf16x8_t*)(pB + 512);
        const bf16x8_t nB2 = *(const bf16x8_t*)(pB + 1024);
        const bf16x8_t nB3 = *(const bf16x8_t*)(pB + 1536);

        acc0 = MFMA16(cA, cB0, acc0);
        acc1 = MFMA16(cA, cB1, acc1);
        acc2 = MFMA16(cA, cB2, acc2);
        acc3 = MFMA16(cA, cB3, acc3);

        cA = nA; cB0 = nB0; cB1 = nB1; cB2 = nB2; cB3 = nB3;
    }

    // wave-private transpose -> coalesced bf16 store
    #pragma unroll
    for (int r = 0; r < 4; ++r) {
        const int row = q * 4 + r;
        T[wv][row][m]      = (__bf16)acc0[r];
        T[wv][row][16 + m] = (__bf16)acc1[r];
        T[wv][row][32 + m] = (__bf16)acc2[r];
        T[wv][row][48 + m] = (__bf16)acc3[r];
    }
    __bf16* dstb = (h ? a_out_p : a_in_p) + (size_t)ksp * kPb + (size_t)b * kN * kD;
    const int ibase = tile * 64 + wv * 16;
    #pragma unroll
    for (int p2 = 0; p2 < 2; ++p2) {
        const int jr = p2 * 8 + (lane >> 3);
        const int c8 = lane & 7;
        const int i  = ibase + jr;
        if (i < kN) {
            const bf16x8_t v = *reinterpret_cast<const bf16x8_t*>(&T[wv][jr][c8 * 8]);
            *reinterpret_cast<bf16x8_t*>(dstb + (size_t)i * kD + c8 * 8) = v;
        }
    }
}

// ---------------------------------------------------------------------------
// Gating, col-split: block = 256 (4 waves), 16 rows per block, wave c owns
// output cols f = c*16..c*16+15. a_in/a_out = f32 sum of 5 bf16 K-partials.
// step 1: write next state + emit step-2 SWTfrag (fused precompute_swt).
// step 2: fused output head.
// ---------------------------------------------------------------------------
__global__ __launch_bounds__(256, 2) void gating(
    const __bf16* __restrict__ a_in_p,   // [5][8000][64] bf16
    const __bf16* __restrict__ a_out_p,
    const float* __restrict__ state,
    const float* __restrict__ W_r,
    const float* __restrict__ W_z,
    const float* __restrict__ W_h,
    float* __restrict__ s_next,
    const float* __restrict__ W_in,      // step 1: SWT emission
    const float* __restrict__ W_out,
    __bf16* __restrict__ SWTfrag,
    const float* __restrict__ ann,
    const float* __restrict__ Wo1,
    const float* __restrict__ Wo2,
    float* __restrict__ out,
    const int step)
{
    const int i0   = blockIdx.x * 16;
    const int tid  = threadIdx.x;
    const int c    = tid >> 6;           // wave = column slice
    const int lane = tid & 63;
    const int m    = lane & 15;
    const int q    = lane >> 4;
    const int f    = c * 16 + m;

    __shared__ __bf16 TL[16][72];
    __shared__ float  Osum[4][16];

    const size_t rowA = (size_t)(i0 + m);

    bf16x8_t xf[6];
    {
        const __bf16* p = a_in_p + rowA * kD + q * 8;
        xf[0] = sum5pb(p);
        xf[1] = sum5pb(p + 32);
        p = a_out_p + rowA * kD + q * 8;
        xf[2] = sum5pb(p);
        xf[3] = sum5pb(p + 32);
        const float* ps = state + rowA * kD + q * 8;
        xf[4] = cvt8(ld4(ps),      ld4(ps + 4));
        xf[5] = cvt8(ld4(ps + 32), ld4(ps + 36));
    }

    f32x4_t accr = {0.f, 0.f, 0.f, 0.f};
    f32x4_t accz = {0.f, 0.f, 0.f, 0.f};
    f32x4_t acch = {0.f, 0.f, 0.f, 0.f};

    const float* wr = W_r + f * 192 + q * 8;
    const float* wz = W_z + f * 192 + q * 8;
    const float* wh = W_h + f * 192 + q * 8;
    #pragma unroll
    for (int kc = 0; kc < 6; ++kc) {
        accr = MFMA16(xf[kc], cvt8(ld4(wr + kc * 32), ld4(wr + kc * 32 + 4)), accr);
        accz = MFMA16(xf[kc], cvt8(ld4(wz + kc * 32), ld4(wz + kc * 32 + 4)), accz);
        if (kc < 4)
            acch = MFMA16(xf[kc], cvt8(ld4(wh + kc * 32), ld4(wh + kc * 32 + 4)), acch);
    }

    float sC[4];
    #pragma unroll
    for (int r = 0; r < 4; ++r)
        sC[r] = state[(size_t)(i0 + q * 4 + r) * kD + f];

    #pragma unroll
    for (int r = 0; r < 4; ++r)
        TL[q * 4 + r][f] = (__bf16)(sigm(accr[r]) * sC[r]);
    __syncthreads();
    const bf16x8_t rs0 = *(const bf16x8_t*)&TL[m][q * 8];
    const bf16x8_t rs1 = *(const bf16x8_t*)&TL[m][32 + q * 8];

    const float* wh3 = W_h + f * 192 + 128 + q * 8;
    acch = MFMA16(rs0, cvt8(ld4(wh3),      ld4(wh3 + 4)),  acch);
    acch = MFMA16(rs1, cvt8(ld4(wh3 + 32), ld4(wh3 + 36)), acch);

    float ns[4];
    #pragma unroll
    for (int r = 0; r < 4; ++r) {
        const float zv = sigm(accz[r]);
        ns[r] = (1.f - zv) * sC[r] + zv * fast_tanh(acch[r]);
    }

    if (step == 1) {
        #pragma unroll
        for (int r = 0; r < 4; ++r)
            s_next[(size_t)(i0 + q * 4 + r) * kD + f] = ns[r];

        // --- fused precompute_swt for step 2 (bit-identical numerics) ---
        __syncthreads();  // all waves done reading rs frags
        #pragma unroll
        for (int r = 0; r < 4; ++r)
            TL[q * 4 + r][f] = (__bf16)ns[r];
        __syncthreads();
        const bf16x8_t sj0 = *(const bf16x8_t*)&TL[m][q * 8];
        const bf16x8_t sj1 = *(const bf16x8_t*)&TL[m][32 + q * 8];

        // this thread's 4 output rows: row0..row0+3 (1000%4==0: no straddle)
        const int row0 = i0 + q * 4;
        const int bb   = row0 / 1000;
        const int jj0  = row0 - bb * 1000;

        #pragma unroll
        for (int u = 0; u < 2; ++u) {
            const int eh = c * 2 + u;        // wave c owns 2 of 8 (h,e) combos
            const int hh = eh >> 2;
            const int ee = eh & 3;
            const float* W = (hh ? W_out : W_in) + ee * kD * kD;
            const int jg0 = ee * 1000 + jj0; // %8 in {0,4}: 4 rows in one octet
            const int s   = jg0 >> 5;
            const int qq  = (jg0 >> 3) & 3;
            const int jo  = jg0 & 7;
            const int bh2 = bb * 2 + hh;
            #pragma unroll
            for (int fg = 0; fg < 4; ++fg) {
                const int fp = fg * 16 + m;
                const float* wrow = W + fp * kD + q * 8;
                const bf16x8_t bf0 = cvt8(ld4(wrow),      ld4(wrow + 4));
                const bf16x8_t bf1 = cvt8(ld4(wrow + 32), ld4(wrow + 36));
                f32x4_t acc = {0.f, 0.f, 0.f, 0.f};
                acc = MFMA16(sj0, bf0, acc);
                acc = MFMA16(sj1, bf1, acc);
                bf16x4_t v;
                v[0] = (__bf16)acc[0]; v[1] = (__bf16)acc[1];
                v[2] = (__bf16)acc[2]; v[3] = (__bf16)acc[3];
                const size_t el =
                    ((((size_t)bh2 * 125 + s) * 4 + fg) * 64 + qq * 16 + m) * 8 + jo;
                *reinterpret_cast<bf16x4_t*>(SWTfrag + el) = v;
            }
        }
    } else {
        __syncthreads();
        #pragma unroll
        for (int r = 0; r < 4; ++r)
            TL[q * 4 + r][f] = (__bf16)ns[r];
        __syncthreads();
        const bf16x8_t j0 = *(const bf16x8_t*)&TL[m][q * 8];
        const bf16x8_t j1 = *(const bf16x8_t*)&TL[m][32 + q * 8];
        const float* ap = ann + rowA * kAD + q * 8;
        const bf16x8_t j2 = cvt8(ld4(ap), ld4(ap + 4));

        f32x4_t acco = {0.f, 0.f, 0.f, 0.f};
        const float* wo = Wo1 + (size_t)f * 96 + q * 8;
        acco = MFMA16(j0, cvt8(ld4(wo),      ld4(wo + 4)),  acco);
        acco = MFMA16(j1, cvt8(ld4(wo + 32), ld4(wo + 36)), acco);
        acco = MFMA16(j2, cvt8(ld4(wo + 64), ld4(wo + 68)), acco);

        const float w2 = Wo2[f];
        float vs[4];
        #pragma unroll
        for (int r = 0; r < 4; ++r)
            vs[r] = fast_tanh(acco[r]) * w2;
        #pragma unroll
        for (int off = 1; off <= 8; off <<= 1) {
            #pragma unroll
            for (int r = 0; r < 4; ++r)
                vs[r] += __shfl_xor(vs[r], off, 64);
        }
        if (m == 0) {
            #pragma unroll
            for (int r = 0; r < 4; ++r)
                Osum[c][q * 4 + r] = vs[r];
        }
        __syncthreads();
        if (tid < 16)
            out[i0 + tid] = Osum[0][tid] + Osum[1][tid] + Osum[2][tid] + Osum[3][tid];
    }
}

extern "C" void kernel_launch(void* const* d_in, const int* in_sizes, int n_in,
                              void* d_out, int out_size, void* d_ws, size_t ws_size,
                              hipStream_t stream) {
    (void)in_sizes; (void)n_in; (void)out_size; (void)ws_size;

    const float* prop_state = (const float*)d_in[0];
    const float* annotation = (const float*)d_in[1];
    const float* A          = (const float*)d_in[2];
    const float* W_in       = (const float*)d_in[3];
    const float* W_out      = (const float*)d_in[4];
    const float* W_r        = (const float*)d_in[5];
    const float* W_z        = (const float*)d_in[6];
    const float* W_h        = (const float*)d_in[7];
    const float* Wo1        = (const float*)d_in[8];
    const float* Wo2        = (const float*)d_in[9];
    float* out = (float*)d_out;

    char* ws = (char*)d_ws;
    __bf16* Afrag   = (__bf16*)(ws);                    // 131,072,000 B
    __bf16* SWTfrag = (__bf16*)(ws + 131072000);        //   8,192,000 B
    __bf16* a_in_p  = (__bf16*)(ws + 139264000);        //   5,120,000 B (5 bf16 planes)
    __bf16* a_out_p = (__bf16*)(ws + 144384000);        //   5,120,000 B
    float*  s1      = (float*)(ws + 149504000);         //   2,048,000 B

    // step 1 (fused: A read + relayout emission + GEMM)
    precompute_swt<<<1024, 256, 0, stream>>>(prop_state, W_in, W_out, SWTfrag);
    fused_mm1<<<1280, 256, 0, stream>>>(A, SWTfrag, Afrag, a_in_p, a_out_p);
    // gating step 1 also emits step-2 SWTfrag (fused precompute_swt)
    gating<<<500, 256, 0, stream>>>(a_in_p, a_out_p, prop_state, W_r, W_z, W_h,
                                    s1, W_in, W_out, SWTfrag,
                                    nullptr, nullptr, nullptr, nullptr, 1);
    // step 2 (+ fused output head)
    big_mm_f<<<1280, 256, 0, stream>>>(Afrag, SWTfrag, a_in_p, a_out_p);
    gating<<<500, 256, 0, stream>>>(a_in_p, a_out_p, s1, W_r, W_z, W_h,
                                    nullptr, nullptr, nullptr, nullptr,
                                    annotation, Wo1, Wo2, out, 2);
}

// Round 4
// 479.944 us; speedup vs baseline: 1.0754x; 1.0036x over previous
//
#include <hip/hip_runtime.h>

// GGNN on MI355X.
// R4: old big_mm was transaction-bound (scattered 128B segments) -> frag relayout.
// R5: all hot global accesses lane-contiguous; 514.9 us. ~340 us is harness floor
//     (1GB ws poison fill + input restore) — untouchable.
// R6: fused relayout_A into step-1 GEMM (fused_mm1); 498.0 us.
// R7: async double-buffer in fused_mm1; only -2.3 us -> mixed-BW-bound. 495.7 us.
// R8: bf16 partial planes + precompute_swt(step2) fused into gating1; 481.7 us.
// R9: kill the 1280-block tail round: both GEMMs now run at exactly 5 blocks/CU
//     (grid 1280 = 256 CU x 5). fused_mm1 back to single-LDS-buffer (17.4 KB,
//     R7 showed overlap is TLP-covered) + __launch_bounds__(256,5); big_mm_f
//     also (256,5). More waves/SIMD for mixed-stream latency hiding.

typedef float  f32x4_t  __attribute__((ext_vector_type(4)));
typedef __bf16 bf16x8_t __attribute__((ext_vector_type(8)));
typedef __bf16 bf16x4_t __attribute__((ext_vector_type(4)));

#define MFMA16(a, b, c) __builtin_amdgcn_mfma_f32_16x16x32_bf16((a), (b), (c), 0, 0, 0)

static constexpr int kN   = 1000;
static constexpr int kD   = 64;
static constexpr int kAD  = 32;
static constexpr int kPb  = 8000 * 64;   // bf16 elems per partial plane
static constexpr int kPl  = 5;           // k-split partial planes

__device__ __forceinline__ float4 ld4(const float* p) {
    return *reinterpret_cast<const float4*>(p);
}

__device__ __forceinline__ bf16x8_t cvt8(float4 a, float4 b) {
    bf16x8_t r;
    r[0] = (__bf16)a.x; r[1] = (__bf16)a.y; r[2] = (__bf16)a.z; r[3] = (__bf16)a.w;
    r[4] = (__bf16)b.x; r[5] = (__bf16)b.y; r[6] = (__bf16)b.z; r[7] = (__bf16)b.w;
    return r;
}

// bf16x8 of f32-sum over kPl bf16 partial planes at stride kPb
__device__ __forceinline__ bf16x8_t sum5pb(const __bf16* p) {
    float s0 = 0.f, s1 = 0.f, s2 = 0.f, s3 = 0.f;
    float s4 = 0.f, s5 = 0.f, s6 = 0.f, s7 = 0.f;
    #pragma unroll
    for (int pl = 0; pl < kPl; ++pl) {
        const bf16x8_t v = *reinterpret_cast<const bf16x8_t*>(p + (size_t)pl * kPb);
        s0 += (float)v[0]; s1 += (float)v[1]; s2 += (float)v[2]; s3 += (float)v[3];
        s4 += (float)v[4]; s5 += (float)v[5]; s6 += (float)v[6]; s7 += (float)v[7];
    }
    bf16x8_t r;
    r[0] = (__bf16)s0; r[1] = (__bf16)s1; r[2] = (__bf16)s2; r[3] = (__bf16)s3;
    r[4] = (__bf16)s4; r[5] = (__bf16)s5; r[6] = (__bf16)s6; r[7] = (__bf16)s7;
    return r;
}

__device__ __forceinline__ float sigm(float x) {
    x = fminf(fmaxf(x, -30.f), 30.f);
    return 1.0f / (1.0f + __expf(-x));
}

__device__ __forceinline__ float fast_tanh(float x) {
    x = fminf(fmaxf(x, -15.f), 15.f);
    const float e = __expf(-2.0f * x);
    return (1.0f - e) / (1.0f + e);
}

// ---------------------------------------------------------------------------
// precompute_swt (step 1 only): SWTfrag in MFMA B-fragment order:
//   el = ((((b*2+h)*125 + s)*4 + c)*64 + lane)*8 + j
//   holds S[f = c*16 + (lane&15)][jg = s*32 + (lane>>4)*8 + j]
// grid 1024 = 16 jt x 4 e x 2 h x 8 b; block 256.
// ---------------------------------------------------------------------------
__global__ __launch_bounds__(256) void precompute_swt(
    const float* __restrict__ state,   // [8000][64]
    const float* __restrict__ W_in,    // [4][64][64]
    const float* __restrict__ W_out,
    __bf16* __restrict__ SWTfrag)
{
    const int bx = blockIdx.x;
    const int jt = bx & 15;
    const int e  = (bx >> 4) & 3;
    const int h  = (bx >> 6) & 1;
    const int b  = bx >> 7;
    const float* W = (h ? W_out : W_in) + e * kD * kD;

    const int tid  = threadIdx.x;
    const int w    = tid >> 6;
    const int lane = tid & 63;
    const int m    = lane & 15;
    const int q    = lane >> 4;

    __shared__ __bf16 T[64][72];  // [f][j_local], +8 pad

    const int  jj    = jt * 64 + w * 16 + m;
    const bool valid = (jj < kN);
    const float* srow = state + ((size_t)b * kN + (valid ? jj : kN - 1)) * kD + q * 8;
    float4 a0 = ld4(srow),      a1 = ld4(srow + 4);
    float4 a2 = ld4(srow + 32), a3 = ld4(srow + 36);
    if (!valid) {
        a0 = make_float4(0.f, 0.f, 0.f, 0.f); a1 = a0; a2 = a0; a3 = a0;
    }
    const bf16x8_t af0 = cvt8(a0, a1);
    const bf16x8_t af1 = cvt8(a2, a3);

    #pragma unroll
    for (int c = 0; c < 4; ++c) {
        const int f = c * 16 + m;
        const float* wrow = W + f * kD + q * 8;
        const bf16x8_t bf0 = cvt8(ld4(wrow),      ld4(wrow + 4));
        const bf16x8_t bf1 = cvt8(ld4(wrow + 32), ld4(wrow + 36));
        f32x4_t acc = {0.f, 0.f, 0.f, 0.f};
        acc = MFMA16(af0, bf0, acc);
        acc = MFMA16(af1, bf1, acc);
        const int j0 = w * 16 + q * 4;
        bf16x4_t v;
        v[0] = (__bf16)acc[0]; v[1] = (__bf16)acc[1];
        v[2] = (__bf16)acc[2]; v[3] = (__bf16)acc[3];
        *reinterpret_cast<bf16x4_t*>(&T[f][j0]) = v;
    }
    __syncthreads();

    const int bh = b * 2 + h;
    #pragma unroll
    for (int rep = 0; rep < 2; ++rep) {
        const int m2 = tid & 15;
        const int cc = (tid >> 4) & 3;
        const int ol = (tid >> 6) + rep * 4;
        const int j0 = jt * 64 + ol * 8;
        if (j0 < kN) {
            const int jg = e * kN + j0;
            const int s  = jg >> 5;
            const int qq = (jg >> 3) & 3;
            const uint4 v = *reinterpret_cast<uint4*>(&T[cc * 16 + m2][ol * 8]);
            const size_t el = ((((size_t)bh * 125 + s) * 4 + cc) * 64 + qq * 16 + m2) * 8;
            *reinterpret_cast<uint4*>((__bf16*)SWTfrag + el) = v;
        }
    }
}

// ---------------------------------------------------------------------------
// fused_mm1: step-1 GEMM reading A (f32) directly + Afrag emission.
// grid 1280 = 16 tile x 5 kseg x 2 h x 8 b; block 256 (4 waves x 16 rows);
// exactly 5 blocks/CU (launch_bounds(256,5), single 17.4 KB LDS buffer).
// Per chunk: stage (ld4+cvt -> LDS), barrier, 4 k-steps of {frag read, Afrag
// store, 4 B loads, 4 MFMA}, barrier. bf16 partial output via per-wave LDS
// transpose (cols 64..127, disjoint from tail-compute reads).
// ---------------------------------------------------------------------------
__global__ __launch_bounds__(256, 5) void fused_mm1(
    const float* __restrict__ A,
    const __bf16* __restrict__ SWTfrag,
    __bf16* __restrict__ Afrag,
    __bf16* __restrict__ a_in_p,       // [5][8000][64] bf16
    __bf16* __restrict__ a_out_p)
{
    const int bx   = blockIdx.x;
    const int tile = bx & 15;
    const int rest = bx >> 4;
    const int kseg = rest % 5;
    const int rhb  = rest / 5;
    const int h    = rhb & 1;
    const int b    = rhb >> 1;

    const int t    = threadIdx.x;
    const int wv   = t >> 6;
    const int lane = t & 63;
    const int m    = lane & 15;
    const int q    = lane >> 4;

    __shared__ __bf16 L[64][136];   // 272B row stride: 16B-aligned, staggered

    const float* Abase = A + (size_t)b * kN * 8000 + h * 4000;
    const int bh = b * 2 + h;

    f32x4_t acc0 = {0.f, 0.f, 0.f, 0.f};
    f32x4_t acc1 = {0.f, 0.f, 0.f, 0.f};
    f32x4_t acc2 = {0.f, 0.f, 0.f, 0.f};
    f32x4_t acc3 = {0.f, 0.f, 0.f, 0.f};

    const __bf16* pBbase = SWTfrag + (size_t)bh * 125 * 2048 + (size_t)lane * 8;
    __bf16* pAout = Afrag +
        ((((size_t)(bh * 64 + tile * 4 + wv)) * 125) * 64 + lane) * 8;

    // stage chunk c into LDS: load f32, cvt to bf16, ds_write_b128.
    auto stage_chunk = [&](int c, bool tail) {
        const int kabs = kseg * 800 + c * 128;
        #pragma unroll
        for (int p = 0; p < 4; ++p) {
            if (p == 0 || !tail) {
                const int idx = p * 256 + t;
                const int r   = tail ? (t >> 2) : (idx >> 4);
                const int c8  = tail ? (t & 3)  : (idx & 15);
                int i = tile * 64 + r;
                if (i >= kN) i = kN - 1;           // dup rows; outputs masked
                const float* src = Abase + (size_t)i * 8000 + kabs + c8 * 8;
                *reinterpret_cast<bf16x8_t*>(&L[r][c8 * 8]) =
                    cvt8(ld4(src), ld4(src + 4));
            }
        }
    };
    auto compute_chunk = [&](int c, int nst) {
        #pragma unroll
        for (int sp = 0; sp < 4; ++sp) {
            if (sp < nst) {
                const int s = kseg * 25 + c * 4 + sp;
                const bf16x8_t af =
                    *reinterpret_cast<const bf16x8_t*>(&L[wv * 16 + m][sp * 32 + q * 8]);
                *reinterpret_cast<bf16x8_t*>(pAout + (size_t)s * 512) = af;

                const __bf16* pB = pBbase + (size_t)s * 2048;
                const bf16x8_t b0 = *(const bf16x8_t*)(pB);
                const bf16x8_t b1 = *(const bf16x8_t*)(pB + 512);
                const bf16x8_t b2 = *(const bf16x8_t*)(pB + 1024);
                const bf16x8_t b3 = *(const bf16x8_t*)(pB + 1536);
                acc0 = MFMA16(af, b0, acc0);
                acc1 = MFMA16(af, b1, acc1);
                acc2 = MFMA16(af, b2, acc2);
                acc3 = MFMA16(af, b3, acc3);
            }
        }
    };

    stage_chunk(0, false);
    __syncthreads();
    #pragma unroll 1
    for (int c = 0; c < 6; ++c) {
        compute_chunk(c, 4);
        __syncthreads();
        stage_chunk(c + 1, c + 1 == 6);
        __syncthreads();
    }
    compute_chunk(6, 1);   // tail reads L cols 0..31 only

    // wave-private bf16 transpose in L cols 64..127 (disjoint from tail read)
    __bf16* Tw = &L[wv * 16][64];   // 16 rows x 64 cols, row stride 136
    #pragma unroll
    for (int r = 0; r < 4; ++r) {
        const int row = q * 4 + r;
        Tw[row * 136 + m]      = (__bf16)acc0[r];
        Tw[row * 136 + 16 + m] = (__bf16)acc1[r];
        Tw[row * 136 + 32 + m] = (__bf16)acc2[r];
        Tw[row * 136 + 48 + m] = (__bf16)acc3[r];
    }
    __bf16* dstb = (h ? a_out_p : a_in_p) + (size_t)kseg * kPb + (size_t)b * kN * kD;
    const int ibase = tile * 64 + wv * 16;
    #pragma unroll
    for (int p2 = 0; p2 < 2; ++p2) {
        const int jr = p2 * 8 + (lane >> 3);
        const int c8 = lane & 7;
        const int i  = ibase + jr;
        if (i < kN) {
            const bf16x8_t v = *reinterpret_cast<const bf16x8_t*>(&Tw[jr * 136 + c8 * 8]);
            *reinterpret_cast<bf16x8_t*>(dstb + (size_t)i * kD + c8 * 8) = v;
        }
    }
}

// ---------------------------------------------------------------------------
// big_mm_f (step 2): grid 1280 = 16 tile x 2 h x 8 b x 5 ksp; block 256;
// exactly 5 blocks/CU. Barrier-free stream; depth-1 register prefetch; bf16
// partial output via wave-private LDS transpose.
// ---------------------------------------------------------------------------
__global__ __launch_bounds__(256, 5) void big_mm_f(
    const __bf16* __restrict__ Afrag,
    const __bf16* __restrict__ SWTfrag,
    __bf16* __restrict__ a_in_p,       // [5][8000][64] bf16
    __bf16* __restrict__ a_out_p)
{
    const int bx   = blockIdx.x;
    const int tile = bx & 15;
    const int h    = (bx >> 4) & 1;
    const int b    = (bx >> 5) & 7;
    const int ksp  = bx >> 8;          // 0..4
    const int t    = threadIdx.x;
    const int wv   = t >> 6;
    const int lane = t & 63;
    const int m    = lane & 15;
    const int q    = lane >> 4;

    __shared__ __bf16 T[4][16][72];    // per-wave C transpose (144B rows, 16B-aligned)

    const int s0 = ksp * 25;
    const int ns = 25;

    const int bh = b * 2 + h;
    const __bf16* pA = Afrag +
        ((((size_t)(bh * 64 + tile * 4 + wv)) * 125 + s0) * 64 + lane) * 8;
    const __bf16* pB = SWTfrag +
        (((size_t)bh * 125 + s0) * 4 * 64) * 8 + (size_t)lane * 8;

    f32x4_t acc0 = {0.f, 0.f, 0.f, 0.f};
    f32x4_t acc1 = {0.f, 0.f, 0.f, 0.f};
    f32x4_t acc2 = {0.f, 0.f, 0.f, 0.f};
    f32x4_t acc3 = {0.f, 0.f, 0.f, 0.f};

    bf16x8_t cA  = *(const bf16x8_t*)(pA);
    bf16x8_t cB0 = *(const bf16x8_t*)(pB);
    bf16x8_t cB1 = *(const bf16x8_t*)(pB + 512);
    bf16x8_t cB2 = *(const bf16x8_t*)(pB + 1024);
    bf16x8_t cB3 = *(const bf16x8_t*)(pB + 1536);

    for (int s = 0; s < ns; ++s) {
        const int adv = (s + 1 < ns) ? 1 : 0;
        pA += adv * 512;
        pB += adv * 2048;
        const bf16x8_t nA  = *(const bf16x8_t*)(pA);
        const bf16x8_t nB0 = *(const bf16x8_t*)(pB);
        const bf16x8_t nB1 = *(const bf16x8_t*)(pB + 512);
        const bf16x8_t nB2 = *(const bf16x8_t*)(pB + 1024);
        const bf16x8_t nB3 = *(const bf16x8_t*)(pB + 1536);

        acc0 = MFMA16(cA, cB0, acc0);
        acc1 = MFMA16(cA, cB1, acc1);
        acc2 = MFMA16(cA, cB2, acc2);
        acc3 = MFMA16(cA, cB3, acc3);

        cA = nA; cB0 = nB0; cB1 = nB1; cB2 = nB2; cB3 = nB3;
    }

    // wave-private transpose -> coalesced bf16 store
    #pragma unroll
    for (int r = 0; r < 4; ++r) {
        const int row = q * 4 + r;
        T[wv][row][m]      = (__bf16)acc0[r];
        T[wv][row][16 + m] = (__bf16)acc1[r];
        T[wv][row][32 + m] = (__bf16)acc2[r];
        T[wv][row][48 + m] = (__bf16)acc3[r];
    }
    __bf16* dstb = (h ? a_out_p : a_in_p) + (size_t)ksp * kPb + (size_t)b * kN * kD;
    const int ibase = tile * 64 + wv * 16;
    #pragma unroll
    for (int p2 = 0; p2 < 2; ++p2) {
        const int jr = p2 * 8 + (lane >> 3);
        const int c8 = lane & 7;
        const int i  = ibase + jr;
        if (i < kN) {
            const bf16x8_t v = *reinterpret_cast<const bf16x8_t*>(&T[wv][jr][c8 * 8]);
            *reinterpret_cast<bf16x8_t*>(dstb + (size_t)i * kD + c8 * 8) = v;
        }
    }
}

// ---------------------------------------------------------------------------
// Gating, col-split: block = 256 (4 waves), 16 rows per block, wave c owns
// output cols f = c*16..c*16+15. a_in/a_out = f32 sum of 5 bf16 K-partials.
// step 1: write next state + emit step-2 SWTfrag (fused precompute_swt).
// step 2: fused output head.
// ---------------------------------------------------------------------------
__global__ __launch_bounds__(256, 2) void gating(
    const __bf16* __restrict__ a_in_p,   // [5][8000][64] bf16
    const __bf16* __restrict__ a_out_p,
    const float* __restrict__ state,
    const float* __restrict__ W_r,
    const float* __restrict__ W_z,
    const float* __restrict__ W_h,
    float* __restrict__ s_next,
    const float* __restrict__ W_in,      // step 1: SWT emission
    const float* __restrict__ W_out,
    __bf16* __restrict__ SWTfrag,
    const float* __restrict__ ann,
    const float* __restrict__ Wo1,
    const float* __restrict__ Wo2,
    float* __restrict__ out,
    const int step)
{
    const int i0   = blockIdx.x * 16;
    const int tid  = threadIdx.x;
    const int c    = tid >> 6;           // wave = column slice
    const int lane = tid & 63;
    const int m    = lane & 15;
    const int q    = lane >> 4;
    const int f    = c * 16 + m;

    __shared__ __bf16 TL[16][72];
    __shared__ float  Osum[4][16];

    const size_t rowA = (size_t)(i0 + m);

    bf16x8_t xf[6];
    {
        const __bf16* p = a_in_p + rowA * kD + q * 8;
        xf[0] = sum5pb(p);
        xf[1] = sum5pb(p + 32);
        p = a_out_p + rowA * kD + q * 8;
        xf[2] = sum5pb(p);
        xf[3] = sum5pb(p + 32);
        const float* ps = state + rowA * kD + q * 8;
        xf[4] = cvt8(ld4(ps),      ld4(ps + 4));
        xf[5] = cvt8(ld4(ps + 32), ld4(ps + 36));
    }

    f32x4_t accr = {0.f, 0.f, 0.f, 0.f};
    f32x4_t accz = {0.f, 0.f, 0.f, 0.f};
    f32x4_t acch = {0.f, 0.f, 0.f, 0.f};

    const float* wr = W_r + f * 192 + q * 8;
    const float* wz = W_z + f * 192 + q * 8;
    const float* wh = W_h + f * 192 + q * 8;
    #pragma unroll
    for (int kc = 0; kc < 6; ++kc) {
        accr = MFMA16(xf[kc], cvt8(ld4(wr + kc * 32), ld4(wr + kc * 32 + 4)), accr);
        accz = MFMA16(xf[kc], cvt8(ld4(wz + kc * 32), ld4(wz + kc * 32 + 4)), accz);
        if (kc < 4)
            acch = MFMA16(xf[kc], cvt8(ld4(wh + kc * 32), ld4(wh + kc * 32 + 4)), acch);
    }

    float sC[4];
    #pragma unroll
    for (int r = 0; r < 4; ++r)
        sC[r] = state[(size_t)(i0 + q * 4 + r) * kD + f];

    #pragma unroll
    for (int r = 0; r < 4; ++r)
        TL[q * 4 + r][f] = (__bf16)(sigm(accr[r]) * sC[r]);
    __syncthreads();
    const bf16x8_t rs0 = *(const bf16x8_t*)&TL[m][q * 8];
    const bf16x8_t rs1 = *(const bf16x8_t*)&TL[m][32 + q * 8];

    const float* wh3 = W_h + f * 192 + 128 + q * 8;
    acch = MFMA16(rs0, cvt8(ld4(wh3),      ld4(wh3 + 4)),  acch);
    acch = MFMA16(rs1, cvt8(ld4(wh3 + 32), ld4(wh3 + 36)), acch);

    float ns[4];
    #pragma unroll
    for (int r = 0; r < 4; ++r) {
        const float zv = sigm(accz[r]);
        ns[r] = (1.f - zv) * sC[r] + zv * fast_tanh(acch[r]);
    }

    if (step == 1) {
        #pragma unroll
        for (int r = 0; r < 4; ++r)
            s_next[(size_t)(i0 + q * 4 + r) * kD + f] = ns[r];

        // --- fused precompute_swt for step 2 (bit-identical numerics) ---
        __syncthreads();  // all waves done reading rs frags
        #pragma unroll
        for (int r = 0; r < 4; ++r)
            TL[q * 4 + r][f] = (__bf16)ns[r];
        __syncthreads();
        const bf16x8_t sj0 = *(const bf16x8_t*)&TL[m][q * 8];
        const bf16x8_t sj1 = *(const bf16x8_t*)&TL[m][32 + q * 8];

        // this thread's 4 output rows: row0..row0+3 (1000%4==0: no straddle)
        const int row0 = i0 + q * 4;
        const int bb   = row0 / 1000;
        const int jj0  = row0 - bb * 1000;

        #pragma unroll
        for (int u = 0; u < 2; ++u) {
            const int eh = c * 2 + u;        // wave c owns 2 of 8 (h,e) combos
            const int hh = eh >> 2;
            const int ee = eh & 3;
            const float* W = (hh ? W_out : W_in) + ee * kD * kD;
            const int jg0 = ee * 1000 + jj0; // %8 in {0,4}: 4 rows in one octet
            const int s   = jg0 >> 5;
            const int qq  = (jg0 >> 3) & 3;
            const int jo  = jg0 & 7;
            const int bh2 = bb * 2 + hh;
            #pragma unroll
            for (int fg = 0; fg < 4; ++fg) {
                const int fp = fg * 16 + m;
                const float* wrow = W + fp * kD + q * 8;
                const bf16x8_t bf0 = cvt8(ld4(wrow),      ld4(wrow + 4));
                const bf16x8_t bf1 = cvt8(ld4(wrow + 32), ld4(wrow + 36));
                f32x4_t acc = {0.f, 0.f, 0.f, 0.f};
                acc = MFMA16(sj0, bf0, acc);
                acc = MFMA16(sj1, bf1, acc);
                bf16x4_t v;
                v[0] = (__bf16)acc[0]; v[1] = (__bf16)acc[1];
                v[2] = (__bf16)acc[2]; v[3] = (__bf16)acc[3];
                const size_t el =
                    ((((size_t)bh2 * 125 + s) * 4 + fg) * 64 + qq * 16 + m) * 8 + jo;
                *reinterpret_cast<bf16x4_t*>(SWTfrag + el) = v;
            }
        }
    } else {
        __syncthreads();
        #pragma unroll
        for (int r = 0; r < 4; ++r)
            TL[q * 4 + r][f] = (__bf16)ns[r];
        __syncthreads();
        const bf16x8_t j0 = *(const bf16x8_t*)&TL[m][q * 8];
        const bf16x8_t j1 = *(const bf16x8_t*)&TL[m][32 + q * 8];
        const float* ap = ann + rowA * kAD + q * 8;
        const bf16x8_t j2 = cvt8(ld4(ap), ld4(ap + 4));

        f32x4_t acco = {0.f, 0.f, 0.f, 0.f};
        const float* wo = Wo1 + (size_t)f * 96 + q * 8;
        acco = MFMA16(j0, cvt8(ld4(wo),      ld4(wo + 4)),  acco);
        acco = MFMA16(j1, cvt8(ld4(wo + 32), ld4(wo + 36)), acco);
        acco = MFMA16(j2, cvt8(ld4(wo + 64), ld4(wo + 68)), acco);

        const float w2 = Wo2[f];
        float vs[4];
        #pragma unroll
        for (int r = 0; r < 4; ++r)
            vs[r] = fast_tanh(acco[r]) * w2;
        #pragma unroll
        for (int off = 1; off <= 8; off <<= 1) {
            #pragma unroll
            for (int r = 0; r < 4; ++r)
                vs[r] += __shfl_xor(vs[r], off, 64);
        }
        if (m == 0) {
            #pragma unroll
            for (int r = 0; r < 4; ++r)
                Osum[c][q * 4 + r] = vs[r];
        }
        __syncthreads();
        if (tid < 16)
            out[i0 + tid] = Osum[0][tid] + Osum[1][tid] + Osum[2][tid] + Osum[3][tid];
    }
}

extern "C" void kernel_launch(void* const* d_in, const int* in_sizes, int n_in,
                              void* d_out, int out_size, void* d_ws, size_t ws_size,
                              hipStream_t stream) {
    (void)in_sizes; (void)n_in; (void)out_size; (void)ws_size;

    const float* prop_state = (const float*)d_in[0];
    const float* annotation = (const float*)d_in[1];
    const float* A          = (const float*)d_in[2];
    const float* W_in       = (const float*)d_in[3];
    const float* W_out      = (const float*)d_in[4];
    const float* W_r        = (const float*)d_in[5];
    const float* W_z        = (const float*)d_in[6];
    const float* W_h        = (const float*)d_in[7];
    const float* Wo1        = (const float*)d_in[8];
    const float* Wo2        = (const float*)d_in[9];
    float* out = (float*)d_out;

    char* ws = (char*)d_ws;
    __bf16* Afrag   = (__bf16*)(ws);                    // 131,072,000 B
    __bf16* SWTfrag = (__bf16*)(ws + 131072000);        //   8,192,000 B
    __bf16* a_in_p  = (__bf16*)(ws + 139264000);        //   5,120,000 B (5 bf16 planes)
    __bf16* a_out_p = (__bf16*)(ws + 144384000);        //   5,120,000 B
    float*  s1      = (float*)(ws + 149504000);         //   2,048,000 B

    // step 1 (fused: A read + relayout emission + GEMM)
    precompute_swt<<<1024, 256, 0, stream>>>(prop_state, W_in, W_out, SWTfrag);
    fused_mm1<<<1280, 256, 0, stream>>>(A, SWTfrag, Afrag, a_in_p, a_out_p);
    // gating step 1 also emits step-2 SWTfrag (fused precompute_swt)
    gating<<<500, 256, 0, stream>>>(a_in_p, a_out_p, prop_state, W_r, W_z, W_h,
                                    s1, W_in, W_out, SWTfrag,
                                    nullptr, nullptr, nullptr, nullptr, 1);
    // step 2 (+ fused output head)
    big_mm_f<<<1280, 256, 0, stream>>>(Afrag, SWTfrag, a_in_p, a_out_p);
    gating<<<500, 256, 0, stream>>>(a_in_p, a_out_p, s1, W_r, W_z, W_h,
                                    nullptr, nullptr, nullptr, nullptr,
                                    annotation, Wo1, Wo2, out, 2);
}